// Round 16
// baseline (1208.127 us; speedup 1.0000x reference)
//
#include <hip/hip_runtime.h>
#include <math.h>

#define G_    1024
#define NPG   126
#define EPG   450
#define NN    (G_*NPG)      // 129024
#define EE    (G_*EPG)      // 460800
#define F_    126
#define EPSV  1e-5f

#define KS32  40                      // 32x32 k-steps: 640/16
#define SEGB_SZ (KS32*4*64*8)         // 81920 shorts per (layer,seg)
#define SMALLB_SZ (4*8*64*8)          // 16384 shorts per 128x128 matrix (16x16 layout)

typedef unsigned short u16;
typedef unsigned int   u32;
typedef __attribute__((ext_vector_type(8))) short bf8v;    // 8 bf16 in 4 VGPRs
typedef __attribute__((ext_vector_type(4))) float f4v;
typedef __attribute__((ext_vector_type(16))) float f16v;   // 32x32 accumulator

union U4 { bf8v v; u32 a[4]; };

__device__ __forceinline__ u16 f2b(float f) {              // RNE f32 -> bf16
    u32 u = __float_as_uint(f);
    u += 0x7FFFu + ((u >> 16) & 1u);
    return (u16)(u >> 16);
}
__device__ __forceinline__ float b2f(u16 s) { return __uint_as_float(((u32)s) << 16); }
__device__ __forceinline__ float b2f_lo(u32 u) { return __uint_as_float(u << 16); }
__device__ __forceinline__ float b2f_hi(u32 u) { return __uint_as_float(u & 0xFFFF0000u); }

// BN(+ReLU)-on-load of an 8-wide bf16 A-fragment; coef = {scale[128], shift[128]}
__device__ __forceinline__ bf8v bn_load(const u16* __restrict__ p,
                                        const float* __restrict__ coef, int k0) {
    U4 r; r.v = *(const bf8v*)p;
    if (!coef) return r.v;
    f4v s0 = *(const f4v*)(coef + k0);
    f4v s1 = *(const f4v*)(coef + k0 + 4);
    f4v h0 = *(const f4v*)(coef + 128 + k0);
    f4v h1 = *(const f4v*)(coef + 128 + k0 + 4);
    float v[8];
#pragma unroll
    for (int i = 0; i < 4; ++i) { v[2 * i] = b2f_lo(r.a[i]); v[2 * i + 1] = b2f_hi(r.a[i]); }
    v[0] = fmaxf(v[0] * s0[0] + h0[0], 0.f); v[1] = fmaxf(v[1] * s0[1] + h0[1], 0.f);
    v[2] = fmaxf(v[2] * s0[2] + h0[2], 0.f); v[3] = fmaxf(v[3] * s0[3] + h0[3], 0.f);
    v[4] = fmaxf(v[4] * s1[0] + h1[0], 0.f); v[5] = fmaxf(v[5] * s1[1] + h1[1], 0.f);
    v[6] = fmaxf(v[6] * s1[2] + h1[2], 0.f); v[7] = fmaxf(v[7] * s1[3] + h1[3], 0.f);
    U4 o;
#pragma unroll
    for (int i = 0; i < 4; ++i) o.a[i] = (u32)f2b(v[2 * i]) | ((u32)f2b(v[2 * i + 1]) << 16);
    return o.v;
}

// ---------------- node embedding ----------------
__global__ void k_embed(const float* __restrict__ x, const float* __restrict__ w,
                        const float* __restrict__ b, u16* __restrict__ hb) {
    int idx = (blockIdx.x * 256 + threadIdx.x) * 8;
    if (idx >= NN * 128) return;
    int n = idx >> 7, f0 = idx & 127;
    float xr[5];
#pragma unroll
    for (int c = 0; c < 5; ++c) xr[c] = x[n * 5 + c];
    float v[8];
#pragma unroll
    for (int j = 0; j < 8; ++j) {
        int f = f0 + j;
        float s = 0.f;
        if (f < F_) {
            s = b[f];
#pragma unroll
            for (int c = 0; c < 5; ++c) s += xr[c] * w[c * F_ + f];
        }
        v[j] = s;
    }
    U4 o;
#pragma unroll
    for (int i = 0; i < 4; ++i) o.a[i] = (u32)f2b(v[2 * i]) | ((u32)f2b(v[2 * i + 1]) << 16);
    *(bf8v*)(hb + idx) = o.v;
}

// ---------------- per-graph CSR build ----------------
__global__ void k_build_csr(const int* __restrict__ src, const int* __restrict__ dst,
                            const int* __restrict__ attr,
                            int* __restrict__ deg, int* __restrict__ rstart,
                            int* __restrict__ epack) {
    int g = blockIdx.x;
    __shared__ int scnt[NPG];
    __shared__ int spos[NPG];
    int t = threadIdx.x;
    for (int j = t; j < NPG; j += blockDim.x) scnt[j] = 0;
    __syncthreads();
    int e0 = g * EPG;
    for (int i = t; i < EPG; i += blockDim.x) {
        int dl = dst[e0 + i] - g * NPG;
        atomicAdd(&scnt[dl], 1);
    }
    __syncthreads();
    if (t == 0) {
        int run = 0;
        for (int j = 0; j < NPG; ++j) { spos[j] = run; run += scnt[j]; }
    }
    __syncthreads();
    for (int j = t; j < NPG; j += blockDim.x) {
        deg[g * NPG + j]    = scnt[j];
        rstart[g * NPG + j] = e0 + spos[j];
    }
    __syncthreads();
    for (int j = t; j < NPG; j += blockDim.x) scnt[j] = 0;
    __syncthreads();
    for (int i = t; i < EPG; i += blockDim.x) {
        int e  = e0 + i;
        int dl = dst[e] - g * NPG;
        int p  = atomicAdd(&scnt[dl], 1);
        epack[e0 + spos[dl] + p] = (src[e] - g * NPG) | (attr[e] << 8);
    }
}

// ---------------- per-node degree scalers ----------------
__global__ void k_node_scalars(const int* __restrict__ deg, const int* __restrict__ deg_hist,
                               float* __restrict__ ampv, float* __restrict__ attv) {
    int n = blockIdx.x * blockDim.x + threadIdx.x;
    if (n >= NN) return;
    float sum = 0.f, sl = 0.f;
#pragma unroll
    for (int b = 0; b < 5; ++b) {
        float dh = (float)deg_hist[b];
        sum += dh;
        sl  += dh * logf((float)b + 1.f);
    }
    float avg_log = sl / sum;
    float cm = fmaxf((float)deg[n], 1.f);
    float la = logf(cm + 1.f);
    ampv[n] = la / avg_log;
    attv[n] = avg_log / la;
}

// ---------------- edge-attr table (fp32) ----------------
__global__ void k_build_etab(const float* __restrict__ edge_tab, const float* __restrict__ enc_w,
                             const float* __restrict__ enc_b, const float* __restrict__ pre_w,
                             const float* __restrict__ pre_b, float* __restrict__ etab) {
    int l = blockIdx.x / 10, a = blockIdx.x % 10;
    __shared__ float tmp[F_];
    int t = threadIdx.x;
    if (t < F_) {
        float s = enc_b[l * F_ + t];
        for (int c = 0; c < 50; ++c) s += edge_tab[a * 50 + c] * enc_w[(l * 50 + c) * F_ + t];
        tmp[t] = s;
    }
    __syncthreads();
    if (t < F_) {
        float s = pre_b[l * F_ + t];
        for (int j = 0; j < F_; ++j) s += tmp[j] * pre_w[((size_t)l * 378 + 252 + j) * F_ + t];
        etab[(l * 10 + a) * F_ + t] = s;
    }
}

// ------------- fold: T[l][seg][k][c] -------------
__global__ void k_fold_T(const float* __restrict__ pre_w, const float* __restrict__ post_w,
                         float* __restrict__ Tbuf) {
    int k = blockIdx.x;
    int y = blockIdx.y;
    int l = y / 3, seg = y % 3;
    int c = threadIdx.x;
    __shared__ float wi[128];
    wi[c] = (k < F_ && c < F_) ? pre_w[((size_t)l * 378 + k) * F_ + c] : 0.f;
    __syncthreads();
    float s = 0.f;
    if (k < F_ && c < F_) {
        const float* pw = post_w + (size_t)l * 1638 * F_;
        if (seg == 0) s = pw[(size_t)k * F_ + c];
        int base = 126 + seg * 504;
        for (int f = 0; f < F_; ++f) {
            float bs = pw[(size_t)(base + f) * F_ + c]
                     + pw[(size_t)(base + 126 + f) * F_ + c]
                     + pw[(size_t)(base + 252 + f) * F_ + c];
            s += wi[f] * bs;
        }
    }
    Tbuf[((size_t)y * 128 + k) * 128 + c] = s;
}

// ------------- Wc (deg==0 correction weights) -------------
__global__ void k_fold_Wc(const float* __restrict__ Tbuf, const float* __restrict__ post_w,
                          const int* __restrict__ deg_hist, float* __restrict__ WcBuf) {
    int idx = blockIdx.x * 256 + threadIdx.x;
    if (idx >= 4 * 128 * 128) return;
    int l = idx >> 14, k = (idx >> 7) & 127, c = idx & 127;
    float dsum = 0.f, dsl = 0.f;
#pragma unroll
    for (int b = 0; b < 5; ++b) {
        float dh = (float)deg_hist[b];
        dsum += dh; dsl += dh * logf((float)b + 1.f);
    }
    float avgl = dsl / dsum;
    float l2 = logf(2.f);
    float amp0 = l2 / avgl, att0 = avgl / l2;
    float t1 = Tbuf[((size_t)(l * 3 + 0) * 128 + k) * 128 + c];
    float t2 = Tbuf[((size_t)(l * 3 + 1) * 128 + k) * 128 + c];
    float t3 = Tbuf[((size_t)(l * 3 + 2) * 128 + k) * 128 + c];
    float b0 = (k < F_ && c < F_) ? post_w[((size_t)l * 1638 + k) * F_ + c] : 0.f;
    WcBuf[((size_t)l * 128 + k) * 128 + c] = -((t1 - b0) + amp0 * t2 + att0 * t3);
}

// ---------------- B prep (128x128, 16x16 frag layout) ----------------
__global__ void k_prep_B128(const float* __restrict__ pre_w, const float* __restrict__ lin_w,
                            const float* __restrict__ WcBuf,
                            u16* __restrict__ wjB, u16* __restrict__ linB,
                            u16* __restrict__ wcB) {
    int idx = blockIdx.x * 256 + threadIdx.x;
    int y = blockIdx.y;
    int l = y & 3, ty = y >> 2;
    int j = idx & 7, lane = (idx >> 3) & 63, pnl = (idx >> 9) & 7, ks = idx >> 12;
    int k = ks * 32 + (lane >> 4) * 8 + j;
    int c = pnl * 16 + (lane & 15);
    float v;
    if (ty == 2) {
        v = WcBuf[((size_t)l * 128 + k) * 128 + c];
    } else {
        const float* W = (ty == 0) ? pre_w + ((size_t)l * 378 + 126) * F_
                                   : lin_w + (size_t)l * F_ * F_;
        v = (k < F_ && c < F_) ? W[(size_t)k * F_ + c] : 0.f;
    }
    u16* out = ((ty == 0) ? wjB : (ty == 1) ? linB : wcB) + (size_t)l * SMALLB_SZ;
    out[idx] = f2b(v);
}

// post B per (l,seg), 32x32 frag layout, virtual K=640
__global__ void k_prep_Bpost(const float* __restrict__ post_w, const float* __restrict__ Tbuf,
                             u16* __restrict__ postB) {
    int idx = blockIdx.x * 256 + threadIdx.x;
    if (idx >= SEGB_SZ) return;
    int y = blockIdx.y;                 // l*3+seg
    int l = y / 3, seg = y % 3;
    int j = idx & 7, lane = (idx >> 3) & 63, cg = (idx >> 9) & 3, ks = idx >> 11;  // ks 0..39
    int c  = cg * 32 + (lane & 31);
    int vk = ks * 16 + (lane >> 5) * 8 + j;
    float val = 0.f;
    if (vk < 128) {
        val = Tbuf[((size_t)y * 128 + vk) * 128 + c];
    } else {
        int kv = vk - 128;
        int f = kv >> 2, t = kv & 3;
        if (f < F_ && c < F_)
            val = post_w[((size_t)l * 1638 + 126 + seg * 504 + t * 126 + f) * F_ + c];
    }
    postB[(size_t)y * SEGB_SZ + idx] = f2b(val);
}

// ------- dual K=128 GEMM (Ps | corr), BN-on-load, B in regs, 4 tiles/block ------------------
__global__ __launch_bounds__(256) void k_psgemm(
        const u16* __restrict__ A0, const float* __restrict__ coef,
        const u16* __restrict__ Bv0, const u16* __restrict__ Bv1,
        u16* __restrict__ C0, u16* __restrict__ C1) {
    const u16* Bv = blockIdx.y ? Bv1 : Bv0;
    u16* C = blockIdx.y ? C1 : C0;
    int lane = threadIdx.x & 63, wid = threadIdx.x >> 6;
    int gq = lane >> 4, r15 = lane & 15;
    int wr = (wid >> 1) * 32, wc = (wid & 1) * 64;
    const u16* bp = Bv + ((size_t)(wc >> 4) * 64 + lane) * 8;
    bf8v bfr[16];
#pragma unroll
    for (int ks = 0; ks < 4; ++ks)
#pragma unroll
        for (int fc = 0; fc < 4; ++fc)
            bfr[ks * 4 + fc] = *(const bf8v*)(bp + (size_t)ks * 4096 + fc * 512);

#pragma unroll
    for (int t = 0; t < 4; ++t) {
        size_t rbase = ((size_t)blockIdx.x * 4 + t) * 64;
        size_t row0 = rbase + wr + r15;
        const u16* a0p = A0 + row0 * 128 + gq * 8;
        const u16* a1p = a0p + 16 * 128;
        f4v acc[2][4];
#pragma unroll
        for (int i = 0; i < 2; ++i)
#pragma unroll
            for (int j = 0; j < 4; ++j) acc[i][j] = (f4v){0.f, 0.f, 0.f, 0.f};
#pragma unroll
        for (int ks = 0; ks < 4; ++ks) {
            int k0 = ks * 32 + gq * 8;
            bf8v a0 = bn_load(a0p + ks * 32, coef, k0);
            bf8v a1 = bn_load(a1p + ks * 32, coef, k0);
#pragma unroll
            for (int fc = 0; fc < 4; ++fc) {
                acc[0][fc] = __builtin_amdgcn_mfma_f32_16x16x32_bf16(a0, bfr[ks * 4 + fc], acc[0][fc], 0, 0, 0);
                acc[1][fc] = __builtin_amdgcn_mfma_f32_16x16x32_bf16(a1, bfr[ks * 4 + fc], acc[1][fc], 0, 0, 0);
            }
        }
        int erow = (int)rbase + wr + gq * 4;
        int ecol = wc + r15;
#pragma unroll
        for (int fc = 0; fc < 4; ++fc) {
            int col = ecol + fc * 16;
#pragma unroll
            for (int fr = 0; fr < 2; ++fr)
#pragma unroll
                for (int r = 0; r < 4; ++r) {
                    size_t row = erow + fr * 16 + r;
                    C[row * 128 + col] = (col < F_) ? f2b(acc[fr][fc][r]) : (u16)0;
                }
        }
    }
}

// ------- wave-uniform per-graph aggregation (8 waves/graph) -> aggb[node][512] bf16 ---------
__global__ __launch_bounds__(512) void k_agg2(
        const u16* __restrict__ Psc,
        const float* __restrict__ etab_l,
        const int* __restrict__ deg, const int* __restrict__ rstart,
        const int* __restrict__ epack,
        u16* __restrict__ aggc, int g0) {
    __shared__ u32  PsL[126 * 65];
    __shared__ float etLo[10 * 64];
    __shared__ float etHi[10 * 64];
    __shared__ u32  epL[EPG];
    __shared__ int  degL[NPG];
    __shared__ int  rlL[NPG];
    int gg = g0 + blockIdx.x;
    int tid = threadIdx.x;
    const u16* psrow = Psc + (size_t)blockIdx.x * NPG * 128;
    for (int i = tid; i < NPG * 16; i += 512) {
        int r = i >> 4, q = i & 15;
        U4 u; u.v = *(const bf8v*)(psrow + (size_t)r * 128 + q * 8);
        u32* dp = &PsL[r * 65 + q * 4];
        dp[0] = u.a[0]; dp[1] = u.a[1]; dp[2] = u.a[2]; dp[3] = u.a[3];
    }
    for (int i = tid; i < 640; i += 512) {
        int a = i >> 6, ln = i & 63;
        int f = 2 * ln;
        etLo[i] = (f < F_) ? etab_l[a * F_ + f] : 0.f;
        etHi[i] = (f + 1 < F_) ? etab_l[a * F_ + f + 1] : 0.f;
    }
    for (int e = tid; e < EPG; e += 512) epL[e] = (u32)epack[(size_t)gg * EPG + e];
    if (tid < NPG) {
        degL[tid] = deg[(size_t)gg * NPG + tid];
        rlL[tid]  = rstart[(size_t)gg * NPG + tid] - gg * EPG;
    }
    __syncthreads();

    int lane = tid & 63, wid = tid >> 6;
    for (int nd = wid; nd < NPG; nd += 8) {
        int dg = degL[nd], rl = rlL[nd];
        float s0 = 0.f, q0 = 0.f, s1 = 0.f, q1 = 0.f;
        float n0 = 3.4e38f, x0 = -3.4e38f, n1 = 3.4e38f, x1 = -3.4e38f;
        for (int e = 0; e < dg; ++e) {
            u32 pk = epL[rl + e];
            int sN = pk & 255, at = pk >> 8;
            u32 pv = PsL[sN * 65 + lane];
            float v0 = b2f_lo(pv) + etLo[at * 64 + lane];
            float v1 = b2f_hi(pv) + etHi[at * 64 + lane];
            s0 += v0; q0 += v0 * v0; n0 = fminf(n0, v0); x0 = fmaxf(x0, v0);
            s1 += v1; q1 += v1 * v1; n1 = fminf(n1, v1); x1 = fmaxf(x1, v1);
        }
        float m0, m1, d0, d1;
        if (dg == 0) {
            m0 = m1 = 0.f; n0 = x0 = n1 = x1 = 0.f;
            d0 = d1 = 0.0031622776601683794f;
        } else {
            float ic = 1.f / (float)dg;
            m0 = s0 * ic; m1 = s1 * ic;
            d0 = sqrtf(fmaxf(q0 * ic - m0 * m0, 0.f) + EPSV);
            d1 = sqrtf(fmaxf(q1 * ic - m1 * m1, 0.f) + EPSV);
        }
        U4 o;
        o.a[0] = (u32)f2b(m0) | ((u32)f2b(n0) << 16);
        o.a[1] = (u32)f2b(x0) | ((u32)f2b(d0) << 16);
        o.a[2] = (u32)f2b(m1) | ((u32)f2b(n1) << 16);
        o.a[3] = (u32)f2b(x1) | ((u32)f2b(d1) << 16);
        *(bf8v*)(aggc + ((size_t)blockIdx.x * NPG + nd) * 512 + lane * 8) = o.v;
    }
}

// ------- post GEMM, 32x32x16 MFMA, wave tile 32 rows x 32 cols, 4 waves/SIMD ----------------
// out = [h|vstat]@(T1;B1) + amp*(..2) + att*(..3) + bias (+corr if deg==0)
__global__ __launch_bounds__(256, 4) void k_post2(
        const u16* __restrict__ hA, const float* __restrict__ coef,
        const u16* __restrict__ aggc, const u16* __restrict__ corr,
        const int* __restrict__ degc,
        const float* __restrict__ ampc, const float* __restrict__ attc,
        const u16* __restrict__ postB_l, const float* __restrict__ bias,
        u16* __restrict__ outC) {
    int lane = threadIdx.x & 63, wid = threadIdx.x >> 6;   // wave = col group 0..3
    int r31 = lane & 31, kg = lane >> 5;
    size_t rbase = (size_t)blockIdx.x * 32;
    const u16* h0 = hA + (rbase + r31) * 128 + kg * 8;
    const u16* g0 = aggc + (rbase + r31) * 512 + kg * 8;
    const u16* bp = postB_l + ((size_t)wid * 64 + lane) * 8;   // + ks*2048 + seg*SEGB_SZ

    f16v acc[3];
#pragma unroll
    for (int s = 0; s < 3; ++s)
#pragma unroll
        for (int r = 0; r < 16; ++r) acc[s][r] = 0.f;

    bf8v bc0 = *(const bf8v*)(bp);
    bf8v bc1 = *(const bf8v*)(bp + SEGB_SZ);
    bf8v bc2 = *(const bf8v*)(bp + 2 * SEGB_SZ);

#pragma unroll 4
    for (int ks = 0; ks < KS32; ++ks) {
        bf8v bn0, bn1, bn2;
        if (ks < KS32 - 1) {
            const u16* bn = bp + (size_t)(ks + 1) * 2048;
            bn0 = *(const bf8v*)(bn);
            bn1 = *(const bf8v*)(bn + SEGB_SZ);
            bn2 = *(const bf8v*)(bn + 2 * SEGB_SZ);
        }
        bf8v a0;
        if (ks < 8) {
            int k0 = ks * 16 + kg * 8;
            a0 = bn_load(h0 + ks * 16, coef, k0);
        } else {
            a0 = *(const bf8v*)(g0 + (ks - 8) * 16);
        }
        acc[0] = __builtin_amdgcn_mfma_f32_32x32x16_bf16(a0, bc0, acc[0], 0, 0, 0);
        acc[1] = __builtin_amdgcn_mfma_f32_32x32x16_bf16(a0, bc1, acc[1], 0, 0, 0);
        acc[2] = __builtin_amdgcn_mfma_f32_32x32x16_bf16(a0, bc2, acc[2], 0, 0, 0);
        bc0 = bn0; bc1 = bn1; bc2 = bn2;
    }

    // epilogue: C/D map (32x32): col = lane&31, row = (r&3) + 8*(r>>2) + 4*(lane>>5)
    int ecol = wid * 32 + r31;
    float bv = (ecol < F_) ? bias[ecol] : 0.f;
#pragma unroll
    for (int r = 0; r < 16; ++r) {
        int rowl = (r & 3) + 8 * (r >> 2) + 4 * kg;
        size_t row = rbase + rowl;
        float am = ampc[row], at = attc[row];
        bool isz = (degc[row] == 0);
        float val = acc[0][r] + am * acc[1][r] + at * acc[2][r];
        u16 ov = 0;
        if (ecol < F_) {
            val += bv;
            if (isz) val += b2f(corr[row * 128 + ecol]);
            ov = f2b(val);
        }
        outC[row * 128 + ecol] = ov;
    }
}

// ------- lin GEMM (K=128) + fused BN stats, B in regs, 4 tiles/block ------------------------
__global__ __launch_bounds__(256) void k_lin(
        const u16* __restrict__ A0, const u16* __restrict__ Bv,
        const float* __restrict__ bias, float* __restrict__ bns,
        u16* __restrict__ C) {
    __shared__ float ldsS[128];
    __shared__ float ldsQ[128];
    int tid = threadIdx.x;
    if (tid < 128) { ldsS[tid] = 0.f; ldsQ[tid] = 0.f; }
    __syncthreads();
    int lane = tid & 63, wid = tid >> 6;
    int gq = lane >> 4, r15 = lane & 15;
    int wr = (wid >> 1) * 32, wc = (wid & 1) * 64;
    const u16* bp = Bv + ((size_t)(wc >> 4) * 64 + lane) * 8;
    bf8v bfr[16];
#pragma unroll
    for (int ks = 0; ks < 4; ++ks)
#pragma unroll
        for (int fc = 0; fc < 4; ++fc)
            bfr[ks * 4 + fc] = *(const bf8v*)(bp + (size_t)ks * 4096 + fc * 512);
    int ecol = wc + r15;
    float bv4[4], sc4[4] = {0.f, 0.f, 0.f, 0.f}, sq4[4] = {0.f, 0.f, 0.f, 0.f};
#pragma unroll
    for (int fc = 0; fc < 4; ++fc) {
        int col = ecol + fc * 16;
        bv4[fc] = (col < F_) ? bias[col] : 0.f;
    }

#pragma unroll
    for (int t = 0; t < 4; ++t) {
        size_t rbase = ((size_t)blockIdx.x * 4 + t) * 64;
        size_t row0 = rbase + wr + r15;
        const u16* a0p = A0 + row0 * 128 + gq * 8;
        const u16* a1p = a0p + 16 * 128;
        f4v acc[2][4];
#pragma unroll
        for (int i = 0; i < 2; ++i)
#pragma unroll
            for (int j = 0; j < 4; ++j) acc[i][j] = (f4v){0.f, 0.f, 0.f, 0.f};
#pragma unroll
        for (int ks = 0; ks < 4; ++ks) {
            bf8v a0 = *(const bf8v*)(a0p + ks * 32);
            bf8v a1 = *(const bf8v*)(a1p + ks * 32);
#pragma unroll
            for (int fc = 0; fc < 4; ++fc) {
                acc[0][fc] = __builtin_amdgcn_mfma_f32_16x16x32_bf16(a0, bfr[ks * 4 + fc], acc[0][fc], 0, 0, 0);
                acc[1][fc] = __builtin_amdgcn_mfma_f32_16x16x32_bf16(a1, bfr[ks * 4 + fc], acc[1][fc], 0, 0, 0);
            }
        }
        int erow = (int)rbase + wr + gq * 4;
#pragma unroll
        for (int fc = 0; fc < 4; ++fc) {
            int col = ecol + fc * 16;
#pragma unroll
            for (int fr = 0; fr < 2; ++fr)
#pragma unroll
                for (int r = 0; r < 4; ++r) {
                    size_t row = erow + fr * 16 + r;
                    float val = acc[fr][fc][r] + bv4[fc];
                    sc4[fc] += val; sq4[fc] += val * val;
                    C[row * 128 + col] = (col < F_) ? f2b(val) : (u16)0;
                }
        }
    }
#pragma unroll
    for (int fc = 0; fc < 4; ++fc) {
        int col = ecol + fc * 16;
        atomicAdd(&ldsS[col], sc4[fc]);
        atomicAdd(&ldsQ[col], sq4[fc]);
    }
    __syncthreads();
    if (tid < 128) {
        atomicAdd(&bns[tid], ldsS[tid]);
        atomicAdd(&bns[128 + tid], ldsQ[tid]);
    }
}

// ---------------- BN coefficients ----------------
__global__ void k_bn_coef(const float* __restrict__ bns, const float* __restrict__ g,
                          const float* __restrict__ b, float* __restrict__ coef) {
    int f = threadIdx.x;
    float sc = 0.f, sh = 0.f;
    if (f < F_) {
        float mu  = bns[f] * (1.f / NN);
        float var = bns[128 + f] * (1.f / NN) - mu * mu;
        float r = rsqrtf(fmaxf(var, 0.f) + EPSV);
        sc = g[f] * r;
        sh = b[f] - mu * sc;
    }
    coef[f] = sc;
    coef[128 + f] = sh;
}

// ---------------- pool (BN-on-load) + 4-layer MLP head (fp32) --------------
__global__ __launch_bounds__(256) void k_pool_mlp(const u16* __restrict__ hb,
        const float* __restrict__ coef,
        const float* __restrict__ w1, const float* __restrict__ b1,
        const float* __restrict__ w2, const float* __restrict__ b2,
        const float* __restrict__ w3, const float* __restrict__ b3,
        const float* __restrict__ w4, const float* __restrict__ b4,
        float* __restrict__ out) {
    int gg = blockIdx.x;
    __shared__ float lsum[16][128];
    __shared__ float p[128];
    __shared__ float z1[100];
    __shared__ float z2[50];
    __shared__ float z3[25];
    int t = threadIdx.x;
    int cg = t & 15, rs = t >> 4;
    float sc[8], sh[8];
#pragma unroll
    for (int j = 0; j < 8; ++j) { sc[j] = coef[cg * 8 + j]; sh[j] = coef[128 + cg * 8 + j]; }
    const u16* hbase = hb + (size_t)gg * NPG * 128 + cg * 8;
    float a8[8] = {};
    for (int r = rs; r < NPG; r += 16) {
        U4 u;
        u.v = *(const bf8v*)(hbase + (size_t)r * 128);
        float v[8];
#pragma unroll
        for (int i = 0; i < 4; ++i) { v[2 * i] = b2f_lo(u.a[i]); v[2 * i + 1] = b2f_hi(u.a[i]); }
#pragma unroll
        for (int j = 0; j < 8; ++j) a8[j] += fmaxf(v[j] * sc[j] + sh[j], 0.f);
    }
#pragma unroll
    for (int j = 0; j < 8; ++j) lsum[rs][cg * 8 + j] = a8[j];
    __syncthreads();
    if (t < 128) {
        float s = 0.f;
#pragma unroll
        for (int k = 0; k < 16; ++k) s += lsum[k][t];
        p[t] = s;
    }
    __syncthreads();
    if (t < 100) {
        float s = b1[t];
        for (int c = 0; c < F_; ++c) s += p[c] * w1[c * 100 + t];
        z1[t] = fmaxf(s, 0.f);
    }
    __syncthreads();
    if (t < 50) {
        float s = b2[t];
        for (int c = 0; c < 100; ++c) s += z1[c] * w2[c * 50 + t];
        z2[t] = fmaxf(s, 0.f);
    }
    __syncthreads();
    if (t < 25) {
        float s = b3[t];
        for (int c = 0; c < 50; ++c) s += z2[c] * w3[c * 25 + t];
        z3[t] = fmaxf(s, 0.f);
    }
    __syncthreads();
    if (t == 0) {
        float s = b4[0];
        for (int c = 0; c < 25; ++c) s += z3[c] * w4[c];
        out[gg] = s;
    }
}

extern "C" void kernel_launch(void* const* d_in, const int* in_sizes, int n_in,
                              void* d_out, int out_size, void* d_ws, size_t ws_size,
                              hipStream_t stream) {
    const float* x        = (const float*)d_in[0];
    const int*   ei       = (const int*)d_in[1];
    const int*   src      = ei;
    const int*   dst      = ei + EE;
    const int*   eattr    = (const int*)d_in[2];
    const int*   deg_hist = (const int*)d_in[4];
    const float* emb1_w = (const float*)d_in[5];
    const float* emb1_b = (const float*)d_in[6];
    const float* edge_tab = (const float*)d_in[7];
    const float* enc_w  = (const float*)d_in[8];
    const float* enc_b  = (const float*)d_in[9];
    const float* pre_w  = (const float*)d_in[10];
    const float* pre_b  = (const float*)d_in[11];
    const float* post_w = (const float*)d_in[12];
    const float* post_b = (const float*)d_in[13];
    const float* lin_w  = (const float*)d_in[14];
    const float* lin_b  = (const float*)d_in[15];
    const float* bn_g   = (const float*)d_in[16];
    const float* bn_b   = (const float*)d_in[17];
    const float* w1 = (const float*)d_in[18];
    const float* b1 = (const float*)d_in[19];
    const float* w2 = (const float*)d_in[20];
    const float* b2 = (const float*)d_in[21];
    const float* w3 = (const float*)d_in[22];
    const float* b3 = (const float*)d_in[23];
    const float* w4 = (const float*)d_in[24];
    const float* b4 = (const float*)d_in[25];
    float* out = (float*)d_out;

    // ---- workspace layout; chunk count chosen from ws_size ----
    size_t fixedB = 0;
    {
        fixedB += 3 * ((size_t)NN * 128 * 2 + 256);          // hb, Ps, outA(=corr)
        fixedB += 4 * 10 * F_ * 4 + 256;                     // etab
        fixedB += (size_t)12 * 128 * 128 * 4 + 256;          // Tbuf
        fixedB += (size_t)4 * 128 * 128 * 4 + 256;           // WcBuf
        fixedB += 2 * (4 * 256 * 4 + 256);                   // bns, coef
        fixedB += 2 * ((size_t)NN * 4 + 256);                // deg, rstart
        fixedB += 2 * ((size_t)NN * 4 + 256);                // ampv, attv
        fixedB += (size_t)EE * 4 + 256;                      // epack
        fixedB += 3 * ((size_t)4 * SMALLB_SZ * 2 + 256);     // wjB, linB, wcB
        fixedB += (size_t)12 * SEGB_SZ * 2 + 256;            // postB
    }
    int nch = (ws_size >= fixedB + (size_t)NN * 512 * 2 + 256) ? 1 : 2;
    int GCH_ = G_ / nch;
    size_t CH_ = (size_t)NN / nch;

    char* base = (char*)d_ws;
    size_t o = 0;
    auto alloc = [&](size_t bytes) { char* r = base + o; o = (o + bytes + 255) & ~(size_t)255; return r; };
    u16*  hb    = (u16*)  alloc((size_t)NN * 128 * 2);
    u16*  Ps    = (u16*)  alloc((size_t)NN * 128 * 2);
    u16*  outA  = (u16*)  alloc((size_t)NN * 128 * 2);   // corr aliases outA
    u16*  aggb  = (u16*)  alloc(CH_ * 512 * 2);
    float* etab = (float*)alloc(4 * 10 * F_ * 4);
    float* Tbuf = (float*)alloc((size_t)12 * 128 * 128 * 4);
    float* WcBuf= (float*)alloc((size_t)4 * 128 * 128 * 4);
    float* bns  = (float*)alloc(4 * 256 * 4);
    float* coef = (float*)alloc(4 * 256 * 4);
    int*  deg    = (int*)alloc((size_t)NN * 4);
    int*  rstart = (int*)alloc((size_t)NN * 4);
    float* ampv  = (float*)alloc((size_t)NN * 4);
    float* attv  = (float*)alloc((size_t)NN * 4);
    int*  epack  = (int*)alloc((size_t)EE * 4);
    u16*  wjB   = (u16*)alloc((size_t)4 * SMALLB_SZ * 2);
    u16*  linB  = (u16*)alloc((size_t)4 * SMALLB_SZ * 2);
    u16*  wcB   = (u16*)alloc((size_t)4 * SMALLB_SZ * 2);
    u16*  postB = (u16*)alloc((size_t)12 * SEGB_SZ * 2);
    u16*  corr  = outA;

    // ---- setup ----
    hipMemsetAsync(bns, 0, 4 * 256 * 4, stream);
    k_embed<<<(NN * 128 / 8 + 255) / 256, 256, 0, stream>>>(x, emb1_w, emb1_b, hb);
    k_build_csr<<<G_, 128, 0, stream>>>(src, dst, eattr, deg, rstart, epack);
    k_node_scalars<<<(NN + 255) / 256, 256, 0, stream>>>(deg, deg_hist, ampv, attv);
    k_build_etab<<<40, 128, 0, stream>>>(edge_tab, enc_w, enc_b, pre_w, pre_b, etab);
    k_fold_T<<<dim3(128, 12), 128, 0, stream>>>(pre_w, post_w, Tbuf);
    k_fold_Wc<<<(4 * 128 * 128 + 255) / 256, 256, 0, stream>>>(Tbuf, post_w, deg_hist, WcBuf);
    k_prep_B128<<<dim3(SMALLB_SZ / 256, 12), 256, 0, stream>>>(pre_w, lin_w, WcBuf, wjB, linB, wcB);
    k_prep_Bpost<<<dim3((SEGB_SZ + 255) / 256, 12), 256, 0, stream>>>(post_w, Tbuf, postB);

    for (int l = 0; l < 4; ++l) {
        const float* coefL = (l == 0) ? nullptr : coef + (size_t)(l - 1) * 256;
        // Ps = bn(h)@Wj ; corr = bn(h)@Wc   (dual via grid.y, 4 tiles/block)
        k_psgemm<<<dim3(NN / 256, 2), 256, 0, stream>>>(
            hb, coefL, wjB + (size_t)l * SMALLB_SZ, wcB + (size_t)l * SMALLB_SZ, Ps, corr);
        for (int c = 0; c < nch; ++c) {
            int g0 = c * GCH_;
            size_t r0 = (size_t)g0 * NPG;
            k_agg2<<<GCH_, 512, 0, stream>>>(Ps + r0 * 128, etab + l * 10 * F_,
                                             deg, rstart, epack, aggb, g0);
            k_post2<<<(int)(CH_ / 32), 256, 0, stream>>>(
                hb + r0 * 128, coefL, aggb, corr + r0 * 128,
                deg + r0, ampv + r0, attv + r0,
                postB + (size_t)(l * 3) * SEGB_SZ, post_b + l * F_, outA + r0 * 128);
        }
        // hb = outA @ lin_w + lin_b, BN stats fused (4 tiles/block)
        k_lin<<<NN / 256, 256, 0, stream>>>(outA, linB + (size_t)l * SMALLB_SZ,
                                            lin_b + l * F_, bns + (size_t)l * 256, hb);
        k_bn_coef<<<1, 128, 0, stream>>>(bns + (size_t)l * 256, bn_g + l * F_, bn_b + l * F_,
                                         coef + (size_t)l * 256);
    }

    k_pool_mlp<<<G_, 256, 0, stream>>>(hb, coef + 3 * 256,
                                       w1, b1, w2, b2, w3, b3, w4, b4, out);
}

// Round 17
// 1200.947 us; speedup vs baseline: 1.0060x; 1.0060x over previous
//
#include <hip/hip_runtime.h>
#include <math.h>

#define G_    1024
#define NPG   126
#define EPG   450
#define NN    (G_*NPG)      // 129024
#define EE    (G_*EPG)      // 460800
#define F_    126
#define EPSV  1e-5f

#define KS32  40                      // 32x32 k-steps: 640/16
#define SEGB_SZ (KS32*4*64*8)         // 81920 shorts per (layer,seg)
#define SMALLB_SZ (4*8*64*8)          // 16384 shorts per 128x128 matrix (16x16 layout)

typedef unsigned short u16;
typedef unsigned int   u32;
typedef __attribute__((ext_vector_type(8))) short bf8v;    // 8 bf16 in 4 VGPRs
typedef __attribute__((ext_vector_type(4))) float f4v;
typedef __attribute__((ext_vector_type(16))) float f16v;   // 32x32 accumulator

union U4 { bf8v v; u32 a[4]; };

__device__ __forceinline__ u16 f2b(float f) {              // RNE f32 -> bf16
    u32 u = __float_as_uint(f);
    u += 0x7FFFu + ((u >> 16) & 1u);
    return (u16)(u >> 16);
}
__device__ __forceinline__ float b2f(u16 s) { return __uint_as_float(((u32)s) << 16); }
__device__ __forceinline__ float b2f_lo(u32 u) { return __uint_as_float(u << 16); }
__device__ __forceinline__ float b2f_hi(u32 u) { return __uint_as_float(u & 0xFFFF0000u); }

// BN(+ReLU)-on-load of an 8-wide bf16 A-fragment; coef = {scale[128], shift[128]}
__device__ __forceinline__ bf8v bn_load(const u16* __restrict__ p,
                                        const float* __restrict__ coef, int k0) {
    U4 r; r.v = *(const bf8v*)p;
    if (!coef) return r.v;
    f4v s0 = *(const f4v*)(coef + k0);
    f4v s1 = *(const f4v*)(coef + k0 + 4);
    f4v h0 = *(const f4v*)(coef + 128 + k0);
    f4v h1 = *(const f4v*)(coef + 128 + k0 + 4);
    float v[8];
#pragma unroll
    for (int i = 0; i < 4; ++i) { v[2 * i] = b2f_lo(r.a[i]); v[2 * i + 1] = b2f_hi(r.a[i]); }
    v[0] = fmaxf(v[0] * s0[0] + h0[0], 0.f); v[1] = fmaxf(v[1] * s0[1] + h0[1], 0.f);
    v[2] = fmaxf(v[2] * s0[2] + h0[2], 0.f); v[3] = fmaxf(v[3] * s0[3] + h0[3], 0.f);
    v[4] = fmaxf(v[4] * s1[0] + h1[0], 0.f); v[5] = fmaxf(v[5] * s1[1] + h1[1], 0.f);
    v[6] = fmaxf(v[6] * s1[2] + h1[2], 0.f); v[7] = fmaxf(v[7] * s1[3] + h1[3], 0.f);
    U4 o;
#pragma unroll
    for (int i = 0; i < 4; ++i) o.a[i] = (u32)f2b(v[2 * i]) | ((u32)f2b(v[2 * i + 1]) << 16);
    return o.v;
}

// ---------------- node embedding ----------------
__global__ void k_embed(const float* __restrict__ x, const float* __restrict__ w,
                        const float* __restrict__ b, u16* __restrict__ hb) {
    int idx = (blockIdx.x * 256 + threadIdx.x) * 8;
    if (idx >= NN * 128) return;
    int n = idx >> 7, f0 = idx & 127;
    float xr[5];
#pragma unroll
    for (int c = 0; c < 5; ++c) xr[c] = x[n * 5 + c];
    float v[8];
#pragma unroll
    for (int j = 0; j < 8; ++j) {
        int f = f0 + j;
        float s = 0.f;
        if (f < F_) {
            s = b[f];
#pragma unroll
            for (int c = 0; c < 5; ++c) s += xr[c] * w[c * F_ + f];
        }
        v[j] = s;
    }
    U4 o;
#pragma unroll
    for (int i = 0; i < 4; ++i) o.a[i] = (u32)f2b(v[2 * i]) | ((u32)f2b(v[2 * i + 1]) << 16);
    *(bf8v*)(hb + idx) = o.v;
}

// ---------------- per-graph CSR build ----------------
__global__ void k_build_csr(const int* __restrict__ src, const int* __restrict__ dst,
                            const int* __restrict__ attr,
                            int* __restrict__ deg, int* __restrict__ rstart,
                            int* __restrict__ epack) {
    int g = blockIdx.x;
    __shared__ int scnt[NPG];
    __shared__ int spos[NPG];
    int t = threadIdx.x;
    for (int j = t; j < NPG; j += blockDim.x) scnt[j] = 0;
    __syncthreads();
    int e0 = g * EPG;
    for (int i = t; i < EPG; i += blockDim.x) {
        int dl = dst[e0 + i] - g * NPG;
        atomicAdd(&scnt[dl], 1);
    }
    __syncthreads();
    if (t == 0) {
        int run = 0;
        for (int j = 0; j < NPG; ++j) { spos[j] = run; run += scnt[j]; }
    }
    __syncthreads();
    for (int j = t; j < NPG; j += blockDim.x) {
        deg[g * NPG + j]    = scnt[j];
        rstart[g * NPG + j] = e0 + spos[j];
    }
    __syncthreads();
    for (int j = t; j < NPG; j += blockDim.x) scnt[j] = 0;
    __syncthreads();
    for (int i = t; i < EPG; i += blockDim.x) {
        int e  = e0 + i;
        int dl = dst[e] - g * NPG;
        int p  = atomicAdd(&scnt[dl], 1);
        epack[e0 + spos[dl] + p] = (src[e] - g * NPG) | (attr[e] << 8);
    }
}

// ---------------- per-node degree scalers ----------------
__global__ void k_node_scalars(const int* __restrict__ deg, const int* __restrict__ deg_hist,
                               float* __restrict__ ampv, float* __restrict__ attv) {
    int n = blockIdx.x * blockDim.x + threadIdx.x;
    if (n >= NN) return;
    float sum = 0.f, sl = 0.f;
#pragma unroll
    for (int b = 0; b < 5; ++b) {
        float dh = (float)deg_hist[b];
        sum += dh;
        sl  += dh * logf((float)b + 1.f);
    }
    float avg_log = sl / sum;
    float cm = fmaxf((float)deg[n], 1.f);
    float la = logf(cm + 1.f);
    ampv[n] = la / avg_log;
    attv[n] = avg_log / la;
}

// ---------------- edge-attr table (fp32) ----------------
__global__ void k_build_etab(const float* __restrict__ edge_tab, const float* __restrict__ enc_w,
                             const float* __restrict__ enc_b, const float* __restrict__ pre_w,
                             const float* __restrict__ pre_b, float* __restrict__ etab) {
    int l = blockIdx.x / 10, a = blockIdx.x % 10;
    __shared__ float tmp[F_];
    int t = threadIdx.x;
    if (t < F_) {
        float s = enc_b[l * F_ + t];
        for (int c = 0; c < 50; ++c) s += edge_tab[a * 50 + c] * enc_w[(l * 50 + c) * F_ + t];
        tmp[t] = s;
    }
    __syncthreads();
    if (t < F_) {
        float s = pre_b[l * F_ + t];
        for (int j = 0; j < F_; ++j) s += tmp[j] * pre_w[((size_t)l * 378 + 252 + j) * F_ + t];
        etab[(l * 10 + a) * F_ + t] = s;
    }
}

// ------------- fold: T[l][seg][k][c] -------------
__global__ void k_fold_T(const float* __restrict__ pre_w, const float* __restrict__ post_w,
                         float* __restrict__ Tbuf) {
    int k = blockIdx.x;
    int y = blockIdx.y;
    int l = y / 3, seg = y % 3;
    int c = threadIdx.x;
    __shared__ float wi[128];
    wi[c] = (k < F_ && c < F_) ? pre_w[((size_t)l * 378 + k) * F_ + c] : 0.f;
    __syncthreads();
    float s = 0.f;
    if (k < F_ && c < F_) {
        const float* pw = post_w + (size_t)l * 1638 * F_;
        if (seg == 0) s = pw[(size_t)k * F_ + c];
        int base = 126 + seg * 504;
        for (int f = 0; f < F_; ++f) {
            float bs = pw[(size_t)(base + f) * F_ + c]
                     + pw[(size_t)(base + 126 + f) * F_ + c]
                     + pw[(size_t)(base + 252 + f) * F_ + c];
            s += wi[f] * bs;
        }
    }
    Tbuf[((size_t)y * 128 + k) * 128 + c] = s;
}

// ------------- Wc (deg==0 correction weights) -------------
__global__ void k_fold_Wc(const float* __restrict__ Tbuf, const float* __restrict__ post_w,
                          const int* __restrict__ deg_hist, float* __restrict__ WcBuf) {
    int idx = blockIdx.x * 256 + threadIdx.x;
    if (idx >= 4 * 128 * 128) return;
    int l = idx >> 14, k = (idx >> 7) & 127, c = idx & 127;
    float dsum = 0.f, dsl = 0.f;
#pragma unroll
    for (int b = 0; b < 5; ++b) {
        float dh = (float)deg_hist[b];
        dsum += dh; dsl += dh * logf((float)b + 1.f);
    }
    float avgl = dsl / dsum;
    float l2 = logf(2.f);
    float amp0 = l2 / avgl, att0 = avgl / l2;
    float t1 = Tbuf[((size_t)(l * 3 + 0) * 128 + k) * 128 + c];
    float t2 = Tbuf[((size_t)(l * 3 + 1) * 128 + k) * 128 + c];
    float t3 = Tbuf[((size_t)(l * 3 + 2) * 128 + k) * 128 + c];
    float b0 = (k < F_ && c < F_) ? post_w[((size_t)l * 1638 + k) * F_ + c] : 0.f;
    WcBuf[((size_t)l * 128 + k) * 128 + c] = -((t1 - b0) + amp0 * t2 + att0 * t3);
}

// ---------------- B prep (128x128, 16x16 frag layout) ----------------
__global__ void k_prep_B128(const float* __restrict__ pre_w, const float* __restrict__ lin_w,
                            const float* __restrict__ WcBuf,
                            u16* __restrict__ wjB, u16* __restrict__ linB,
                            u16* __restrict__ wcB) {
    int idx = blockIdx.x * 256 + threadIdx.x;
    int y = blockIdx.y;
    int l = y & 3, ty = y >> 2;
    int j = idx & 7, lane = (idx >> 3) & 63, pnl = (idx >> 9) & 7, ks = idx >> 12;
    int k = ks * 32 + (lane >> 4) * 8 + j;
    int c = pnl * 16 + (lane & 15);
    float v;
    if (ty == 2) {
        v = WcBuf[((size_t)l * 128 + k) * 128 + c];
    } else {
        const float* W = (ty == 0) ? pre_w + ((size_t)l * 378 + 126) * F_
                                   : lin_w + (size_t)l * F_ * F_;
        v = (k < F_ && c < F_) ? W[(size_t)k * F_ + c] : 0.f;
    }
    u16* out = ((ty == 0) ? wjB : (ty == 1) ? linB : wcB) + (size_t)l * SMALLB_SZ;
    out[idx] = f2b(v);
}

// post B per (l,seg), 32x32 frag layout, virtual K=640
__global__ void k_prep_Bpost(const float* __restrict__ post_w, const float* __restrict__ Tbuf,
                             u16* __restrict__ postB) {
    int idx = blockIdx.x * 256 + threadIdx.x;
    if (idx >= SEGB_SZ) return;
    int y = blockIdx.y;                 // l*3+seg
    int l = y / 3, seg = y % 3;
    int j = idx & 7, lane = (idx >> 3) & 63, cg = (idx >> 9) & 3, ks = idx >> 11;  // ks 0..39
    int c  = cg * 32 + (lane & 31);
    int vk = ks * 16 + (lane >> 5) * 8 + j;
    float val = 0.f;
    if (vk < 128) {
        val = Tbuf[((size_t)y * 128 + vk) * 128 + c];
    } else {
        int kv = vk - 128;
        int f = kv >> 2, t = kv & 3;
        if (f < F_ && c < F_)
            val = post_w[((size_t)l * 1638 + 126 + seg * 504 + t * 126 + f) * F_ + c];
    }
    postB[(size_t)y * SEGB_SZ + idx] = f2b(val);
}

// ------- dual K=128 GEMM (Ps | corr), BN-on-load, B in regs, 4 tiles/block ------------------
__global__ __launch_bounds__(256) void k_psgemm(
        const u16* __restrict__ A0, const float* __restrict__ coef,
        const u16* __restrict__ Bv0, const u16* __restrict__ Bv1,
        u16* __restrict__ C0, u16* __restrict__ C1) {
    const u16* Bv = blockIdx.y ? Bv1 : Bv0;
    u16* C = blockIdx.y ? C1 : C0;
    int lane = threadIdx.x & 63, wid = threadIdx.x >> 6;
    int gq = lane >> 4, r15 = lane & 15;
    int wr = (wid >> 1) * 32, wc = (wid & 1) * 64;
    const u16* bp = Bv + ((size_t)(wc >> 4) * 64 + lane) * 8;
    bf8v bfr[16];
#pragma unroll
    for (int ks = 0; ks < 4; ++ks)
#pragma unroll
        for (int fc = 0; fc < 4; ++fc)
            bfr[ks * 4 + fc] = *(const bf8v*)(bp + (size_t)ks * 4096 + fc * 512);

#pragma unroll
    for (int t = 0; t < 4; ++t) {
        size_t rbase = ((size_t)blockIdx.x * 4 + t) * 64;
        size_t row0 = rbase + wr + r15;
        const u16* a0p = A0 + row0 * 128 + gq * 8;
        const u16* a1p = a0p + 16 * 128;
        f4v acc[2][4];
#pragma unroll
        for (int i = 0; i < 2; ++i)
#pragma unroll
            for (int j = 0; j < 4; ++j) acc[i][j] = (f4v){0.f, 0.f, 0.f, 0.f};
#pragma unroll
        for (int ks = 0; ks < 4; ++ks) {
            int k0 = ks * 32 + gq * 8;
            bf8v a0 = bn_load(a0p + ks * 32, coef, k0);
            bf8v a1 = bn_load(a1p + ks * 32, coef, k0);
#pragma unroll
            for (int fc = 0; fc < 4; ++fc) {
                acc[0][fc] = __builtin_amdgcn_mfma_f32_16x16x32_bf16(a0, bfr[ks * 4 + fc], acc[0][fc], 0, 0, 0);
                acc[1][fc] = __builtin_amdgcn_mfma_f32_16x16x32_bf16(a1, bfr[ks * 4 + fc], acc[1][fc], 0, 0, 0);
            }
        }
        int erow = (int)rbase + wr + gq * 4;
        int ecol = wc + r15;
#pragma unroll
        for (int fc = 0; fc < 4; ++fc) {
            int col = ecol + fc * 16;
#pragma unroll
            for (int fr = 0; fr < 2; ++fr)
#pragma unroll
                for (int r = 0; r < 4; ++r) {
                    size_t row = erow + fr * 16 + r;
                    C[row * 128 + col] = (col < F_) ? f2b(acc[fr][fc][r]) : (u16)0;
                }
        }
    }
}

// ------- wave-uniform per-graph aggregation (8 waves/graph) -> aggb[node][512] bf16 ---------
__global__ __launch_bounds__(512) void k_agg2(
        const u16* __restrict__ Psc,
        const float* __restrict__ etab_l,
        const int* __restrict__ deg, const int* __restrict__ rstart,
        const int* __restrict__ epack,
        u16* __restrict__ aggc, int g0) {
    __shared__ u32  PsL[126 * 65];
    __shared__ float etLo[10 * 64];
    __shared__ float etHi[10 * 64];
    __shared__ u32  epL[EPG];
    __shared__ int  degL[NPG];
    __shared__ int  rlL[NPG];
    int gg = g0 + blockIdx.x;
    int tid = threadIdx.x;
    const u16* psrow = Psc + (size_t)blockIdx.x * NPG * 128;
    for (int i = tid; i < NPG * 16; i += 512) {
        int r = i >> 4, q = i & 15;
        U4 u; u.v = *(const bf8v*)(psrow + (size_t)r * 128 + q * 8);
        u32* dp = &PsL[r * 65 + q * 4];
        dp[0] = u.a[0]; dp[1] = u.a[1]; dp[2] = u.a[2]; dp[3] = u.a[3];
    }
    for (int i = tid; i < 640; i += 512) {
        int a = i >> 6, ln = i & 63;
        int f = 2 * ln;
        etLo[i] = (f < F_) ? etab_l[a * F_ + f] : 0.f;
        etHi[i] = (f + 1 < F_) ? etab_l[a * F_ + f + 1] : 0.f;
    }
    for (int e = tid; e < EPG; e += 512) epL[e] = (u32)epack[(size_t)gg * EPG + e];
    if (tid < NPG) {
        degL[tid] = deg[(size_t)gg * NPG + tid];
        rlL[tid]  = rstart[(size_t)gg * NPG + tid] - gg * EPG;
    }
    __syncthreads();

    int lane = tid & 63, wid = tid >> 6;
    for (int nd = wid; nd < NPG; nd += 8) {
        int dg = degL[nd], rl = rlL[nd];
        float s0 = 0.f, q0 = 0.f, s1 = 0.f, q1 = 0.f;
        float n0 = 3.4e38f, x0 = -3.4e38f, n1 = 3.4e38f, x1 = -3.4e38f;
        for (int e = 0; e < dg; ++e) {
            u32 pk = epL[rl + e];
            int sN = pk & 255, at = pk >> 8;
            u32 pv = PsL[sN * 65 + lane];
            float v0 = b2f_lo(pv) + etLo[at * 64 + lane];
            float v1 = b2f_hi(pv) + etHi[at * 64 + lane];
            s0 += v0; q0 += v0 * v0; n0 = fminf(n0, v0); x0 = fmaxf(x0, v0);
            s1 += v1; q1 += v1 * v1; n1 = fminf(n1, v1); x1 = fmaxf(x1, v1);
        }
        float m0, m1, d0, d1;
        if (dg == 0) {
            m0 = m1 = 0.f; n0 = x0 = n1 = x1 = 0.f;
            d0 = d1 = 0.0031622776601683794f;
        } else {
            float ic = 1.f / (float)dg;
            m0 = s0 * ic; m1 = s1 * ic;
            d0 = sqrtf(fmaxf(q0 * ic - m0 * m0, 0.f) + EPSV);
            d1 = sqrtf(fmaxf(q1 * ic - m1 * m1, 0.f) + EPSV);
        }
        U4 o;
        o.a[0] = (u32)f2b(m0) | ((u32)f2b(n0) << 16);
        o.a[1] = (u32)f2b(x0) | ((u32)f2b(d0) << 16);
        o.a[2] = (u32)f2b(m1) | ((u32)f2b(n1) << 16);
        o.a[3] = (u32)f2b(x1) | ((u32)f2b(d1) << 16);
        *(bf8v*)(aggc + ((size_t)blockIdx.x * NPG + nd) * 512 + lane * 8) = o.v;
    }
}

// ------- post GEMM, 32x32x16 MFMA, wave tile 64 rows x 32 cols, fully unrolled --------------
// out = [h|vstat]@(T1;B1) + amp*(..2) + att*(..3) + bias (+corr if deg==0)
__global__ __launch_bounds__(256) void k_post2(
        const u16* __restrict__ hA, const float* __restrict__ coef,
        const u16* __restrict__ aggc, const u16* __restrict__ corr,
        const int* __restrict__ degc,
        const float* __restrict__ ampc, const float* __restrict__ attc,
        const u16* __restrict__ postB_l, const float* __restrict__ bias,
        u16* __restrict__ outC) {
    int lane = threadIdx.x & 63, wid = threadIdx.x >> 6;   // wave = col group 0..3
    int r31 = lane & 31, kg = lane >> 5;
    size_t rbase = (size_t)blockIdx.x * 64;
    const u16* h0 = hA + (rbase + r31) * 128 + kg * 8;
    const u16* h1 = h0 + 32 * 128;
    const u16* g0 = aggc + (rbase + r31) * 512 + kg * 8;
    const u16* g1 = g0 + 32 * 512;
    const u16* bp = postB_l + ((size_t)wid * 64 + lane) * 8;   // + ks*2048 + seg*SEGB_SZ

    f16v acc[3][2];
#pragma unroll
    for (int s = 0; s < 3; ++s)
#pragma unroll
        for (int i = 0; i < 2; ++i)
#pragma unroll
            for (int r = 0; r < 16; ++r) acc[s][i][r] = 0.f;

    // h segment: ks 0..7 (virtual K 0..127), BN-on-load
#pragma unroll
    for (int ks = 0; ks < 8; ++ks) {
        int k0 = ks * 16 + kg * 8;
        bf8v a0 = bn_load(h0 + ks * 16, coef, k0);
        bf8v a1 = bn_load(h1 + ks * 16, coef, k0);
        const u16* bk = bp + (size_t)ks * 2048;
        bf8v b0 = *(const bf8v*)(bk);
        bf8v b1 = *(const bf8v*)(bk + SEGB_SZ);
        bf8v b2 = *(const bf8v*)(bk + 2 * SEGB_SZ);
        acc[0][0] = __builtin_amdgcn_mfma_f32_32x32x16_bf16(a0, b0, acc[0][0], 0, 0, 0);
        acc[0][1] = __builtin_amdgcn_mfma_f32_32x32x16_bf16(a1, b0, acc[0][1], 0, 0, 0);
        acc[1][0] = __builtin_amdgcn_mfma_f32_32x32x16_bf16(a0, b1, acc[1][0], 0, 0, 0);
        acc[1][1] = __builtin_amdgcn_mfma_f32_32x32x16_bf16(a1, b1, acc[1][1], 0, 0, 0);
        acc[2][0] = __builtin_amdgcn_mfma_f32_32x32x16_bf16(a0, b2, acc[2][0], 0, 0, 0);
        acc[2][1] = __builtin_amdgcn_mfma_f32_32x32x16_bf16(a1, b2, acc[2][1], 0, 0, 0);
    }
    // vstat segment: ks 8..39
#pragma unroll
    for (int ks = 8; ks < KS32; ++ks) {
        int off = (ks - 8) * 16;
        bf8v a0 = *(const bf8v*)(g0 + off);
        bf8v a1 = *(const bf8v*)(g1 + off);
        const u16* bk = bp + (size_t)ks * 2048;
        bf8v b0 = *(const bf8v*)(bk);
        bf8v b1 = *(const bf8v*)(bk + SEGB_SZ);
        bf8v b2 = *(const bf8v*)(bk + 2 * SEGB_SZ);
        acc[0][0] = __builtin_amdgcn_mfma_f32_32x32x16_bf16(a0, b0, acc[0][0], 0, 0, 0);
        acc[0][1] = __builtin_amdgcn_mfma_f32_32x32x16_bf16(a1, b0, acc[0][1], 0, 0, 0);
        acc[1][0] = __builtin_amdgcn_mfma_f32_32x32x16_bf16(a0, b1, acc[1][0], 0, 0, 0);
        acc[1][1] = __builtin_amdgcn_mfma_f32_32x32x16_bf16(a1, b1, acc[1][1], 0, 0, 0);
        acc[2][0] = __builtin_amdgcn_mfma_f32_32x32x16_bf16(a0, b2, acc[2][0], 0, 0, 0);
        acc[2][1] = __builtin_amdgcn_mfma_f32_32x32x16_bf16(a1, b2, acc[2][1], 0, 0, 0);
    }

    // epilogue: C/D map (32x32): col = lane&31, row = (r&3) + 8*(r>>2) + 4*(lane>>5)
    int ecol = wid * 32 + r31;
    float bv = (ecol < F_) ? bias[ecol] : 0.f;
#pragma unroll
    for (int rf = 0; rf < 2; ++rf) {
#pragma unroll
        for (int r = 0; r < 16; ++r) {
            int rowl = rf * 32 + (r & 3) + 8 * (r >> 2) + 4 * kg;
            size_t row = rbase + rowl;
            float am = ampc[row], at = attc[row];
            bool isz = (degc[row] == 0);
            float val = acc[0][rf][r] + am * acc[1][rf][r] + at * acc[2][rf][r];
            u16 ov = 0;
            if (ecol < F_) {
                val += bv;
                if (isz) val += b2f(corr[row * 128 + ecol]);
                ov = f2b(val);
            }
            outC[row * 128 + ecol] = ov;
        }
    }
}

// ------- lin GEMM (K=128) + fused BN stats, B in regs, 4 tiles/block ------------------------
__global__ __launch_bounds__(256) void k_lin(
        const u16* __restrict__ A0, const u16* __restrict__ Bv,
        const float* __restrict__ bias, float* __restrict__ bns,
        u16* __restrict__ C) {
    __shared__ float ldsS[128];
    __shared__ float ldsQ[128];
    int tid = threadIdx.x;
    if (tid < 128) { ldsS[tid] = 0.f; ldsQ[tid] = 0.f; }
    __syncthreads();
    int lane = tid & 63, wid = tid >> 6;
    int gq = lane >> 4, r15 = lane & 15;
    int wr = (wid >> 1) * 32, wc = (wid & 1) * 64;
    const u16* bp = Bv + ((size_t)(wc >> 4) * 64 + lane) * 8;
    bf8v bfr[16];
#pragma unroll
    for (int ks = 0; ks < 4; ++ks)
#pragma unroll
        for (int fc = 0; fc < 4; ++fc)
            bfr[ks * 4 + fc] = *(const bf8v*)(bp + (size_t)ks * 4096 + fc * 512);
    int ecol = wc + r15;
    float bv4[4], sc4[4] = {0.f, 0.f, 0.f, 0.f}, sq4[4] = {0.f, 0.f, 0.f, 0.f};
#pragma unroll
    for (int fc = 0; fc < 4; ++fc) {
        int col = ecol + fc * 16;
        bv4[fc] = (col < F_) ? bias[col] : 0.f;
    }

#pragma unroll
    for (int t = 0; t < 4; ++t) {
        size_t rbase = ((size_t)blockIdx.x * 4 + t) * 64;
        size_t row0 = rbase + wr + r15;
        const u16* a0p = A0 + row0 * 128 + gq * 8;
        const u16* a1p = a0p + 16 * 128;
        f4v acc[2][4];
#pragma unroll
        for (int i = 0; i < 2; ++i)
#pragma unroll
            for (int j = 0; j < 4; ++j) acc[i][j] = (f4v){0.f, 0.f, 0.f, 0.f};
#pragma unroll
        for (int ks = 0; ks < 4; ++ks) {
            bf8v a0 = *(const bf8v*)(a0p + ks * 32);
            bf8v a1 = *(const bf8v*)(a1p + ks * 32);
#pragma unroll
            for (int fc = 0; fc < 4; ++fc) {
                acc[0][fc] = __builtin_amdgcn_mfma_f32_16x16x32_bf16(a0, bfr[ks * 4 + fc], acc[0][fc], 0, 0, 0);
                acc[1][fc] = __builtin_amdgcn_mfma_f32_16x16x32_bf16(a1, bfr[ks * 4 + fc], acc[1][fc], 0, 0, 0);
            }
        }
        int erow = (int)rbase + wr + gq * 4;
#pragma unroll
        for (int fc = 0; fc < 4; ++fc) {
            int col = ecol + fc * 16;
#pragma unroll
            for (int fr = 0; fr < 2; ++fr)
#pragma unroll
                for (int r = 0; r < 4; ++r) {
                    size_t row = erow + fr * 16 + r;
                    float val = acc[fr][fc][r] + bv4[fc];
                    sc4[fc] += val; sq4[fc] += val * val;
                    C[row * 128 + col] = (col < F_) ? f2b(val) : (u16)0;
                }
        }
    }
#pragma unroll
    for (int fc = 0; fc < 4; ++fc) {
        int col = ecol + fc * 16;
        atomicAdd(&ldsS[col], sc4[fc]);
        atomicAdd(&ldsQ[col], sq4[fc]);
    }
    __syncthreads();
    if (tid < 128) {
        atomicAdd(&bns[tid], ldsS[tid]);
        atomicAdd(&bns[128 + tid], ldsQ[tid]);
    }
}

// ---------------- BN coefficients ----------------
__global__ void k_bn_coef(const float* __restrict__ bns, const float* __restrict__ g,
                          const float* __restrict__ b, float* __restrict__ coef) {
    int f = threadIdx.x;
    float sc = 0.f, sh = 0.f;
    if (f < F_) {
        float mu  = bns[f] * (1.f / NN);
        float var = bns[128 + f] * (1.f / NN) - mu * mu;
        float r = rsqrtf(fmaxf(var, 0.f) + EPSV);
        sc = g[f] * r;
        sh = b[f] - mu * sc;
    }
    coef[f] = sc;
    coef[128 + f] = sh;
}

// ---------------- pool (BN-on-load) + 4-layer MLP head (fp32) --------------
__global__ __launch_bounds__(256) void k_pool_mlp(const u16* __restrict__ hb,
        const float* __restrict__ coef,
        const float* __restrict__ w1, const float* __restrict__ b1,
        const float* __restrict__ w2, const float* __restrict__ b2,
        const float* __restrict__ w3, const float* __restrict__ b3,
        const float* __restrict__ w4, const float* __restrict__ b4,
        float* __restrict__ out) {
    int gg = blockIdx.x;
    __shared__ float lsum[16][128];
    __shared__ float p[128];
    __shared__ float z1[100];
    __shared__ float z2[50];
    __shared__ float z3[25];
    int t = threadIdx.x;
    int cg = t & 15, rs = t >> 4;
    float sc[8], sh[8];
#pragma unroll
    for (int j = 0; j < 8; ++j) { sc[j] = coef[cg * 8 + j]; sh[j] = coef[128 + cg * 8 + j]; }
    const u16* hbase = hb + (size_t)gg * NPG * 128 + cg * 8;
    float a8[8] = {};
    for (int r = rs; r < NPG; r += 16) {
        U4 u;
        u.v = *(const bf8v*)(hbase + (size_t)r * 128);
        float v[8];
#pragma unroll
        for (int i = 0; i < 4; ++i) { v[2 * i] = b2f_lo(u.a[i]); v[2 * i + 1] = b2f_hi(u.a[i]); }
#pragma unroll
        for (int j = 0; j < 8; ++j) a8[j] += fmaxf(v[j] * sc[j] + sh[j], 0.f);
    }
#pragma unroll
    for (int j = 0; j < 8; ++j) lsum[rs][cg * 8 + j] = a8[j];
    __syncthreads();
    if (t < 128) {
        float s = 0.f;
#pragma unroll
        for (int k = 0; k < 16; ++k) s += lsum[k][t];
        p[t] = s;
    }
    __syncthreads();
    if (t < 100) {
        float s = b1[t];
        for (int c = 0; c < F_; ++c) s += p[c] * w1[c * 100 + t];
        z1[t] = fmaxf(s, 0.f);
    }
    __syncthreads();
    if (t < 50) {
        float s = b2[t];
        for (int c = 0; c < 100; ++c) s += z1[c] * w2[c * 50 + t];
        z2[t] = fmaxf(s, 0.f);
    }
    __syncthreads();
    if (t < 25) {
        float s = b3[t];
        for (int c = 0; c < 50; ++c) s += z2[c] * w3[c * 25 + t];
        z3[t] = fmaxf(s, 0.f);
    }
    __syncthreads();
    if (t == 0) {
        float s = b4[0];
        for (int c = 0; c < 25; ++c) s += z3[c] * w4[c];
        out[gg] = s;
    }
}

extern "C" void kernel_launch(void* const* d_in, const int* in_sizes, int n_in,
                              void* d_out, int out_size, void* d_ws, size_t ws_size,
                              hipStream_t stream) {
    const float* x        = (const float*)d_in[0];
    const int*   ei       = (const int*)d_in[1];
    const int*   src      = ei;
    const int*   dst      = ei + EE;
    const int*   eattr    = (const int*)d_in[2];
    const int*   deg_hist = (const int*)d_in[4];
    const float* emb1_w = (const float*)d_in[5];
    const float* emb1_b = (const float*)d_in[6];
    const float* edge_tab = (const float*)d_in[7];
    const float* enc_w  = (const float*)d_in[8];
    const float* enc_b  = (const float*)d_in[9];
    const float* pre_w  = (const float*)d_in[10];
    const float* pre_b  = (const float*)d_in[11];
    const float* post_w = (const float*)d_in[12];
    const float* post_b = (const float*)d_in[13];
    const float* lin_w  = (const float*)d_in[14];
    const float* lin_b  = (const float*)d_in[15];
    const float* bn_g   = (const float*)d_in[16];
    const float* bn_b   = (const float*)d_in[17];
    const float* w1 = (const float*)d_in[18];
    const float* b1 = (const float*)d_in[19];
    const float* w2 = (const float*)d_in[20];
    const float* b2 = (const float*)d_in[21];
    const float* w3 = (const float*)d_in[22];
    const float* b3 = (const float*)d_in[23];
    const float* w4 = (const float*)d_in[24];
    const float* b4 = (const float*)d_in[25];
    float* out = (float*)d_out;

    // ---- workspace layout; chunk count chosen from ws_size ----
    size_t fixedB = 0;
    {
        fixedB += 3 * ((size_t)NN * 128 * 2 + 256);          // hb, Ps, outA(=corr)
        fixedB += 4 * 10 * F_ * 4 + 256;                     // etab
        fixedB += (size_t)12 * 128 * 128 * 4 + 256;          // Tbuf
        fixedB += (size_t)4 * 128 * 128 * 4 + 256;           // WcBuf
        fixedB += 2 * (4 * 256 * 4 + 256);                   // bns, coef
        fixedB += 2 * ((size_t)NN * 4 + 256);                // deg, rstart
        fixedB += 2 * ((size_t)NN * 4 + 256);                // ampv, attv
        fixedB += (size_t)EE * 4 + 256;                      // epack
        fixedB += 3 * ((size_t)4 * SMALLB_SZ * 2 + 256);     // wjB, linB, wcB
        fixedB += (size_t)12 * SEGB_SZ * 2 + 256;            // postB
    }
    int nch = (ws_size >= fixedB + (size_t)NN * 512 * 2 + 256) ? 1 : 2;
    int GCH_ = G_ / nch;
    size_t CH_ = (size_t)NN / nch;

    char* base = (char*)d_ws;
    size_t o = 0;
    auto alloc = [&](size_t bytes) { char* r = base + o; o = (o + bytes + 255) & ~(size_t)255; return r; };
    u16*  hb    = (u16*)  alloc((size_t)NN * 128 * 2);
    u16*  Ps    = (u16*)  alloc((size_t)NN * 128 * 2);
    u16*  outA  = (u16*)  alloc((size_t)NN * 128 * 2);   // corr aliases outA
    u16*  aggb  = (u16*)  alloc(CH_ * 512 * 2);
    float* etab = (float*)alloc(4 * 10 * F_ * 4);
    float* Tbuf = (float*)alloc((size_t)12 * 128 * 128 * 4);
    float* WcBuf= (float*)alloc((size_t)4 * 128 * 128 * 4);
    float* bns  = (float*)alloc(4 * 256 * 4);
    float* coef = (float*)alloc(4 * 256 * 4);
    int*  deg    = (int*)alloc((size_t)NN * 4);
    int*  rstart = (int*)alloc((size_t)NN * 4);
    float* ampv  = (float*)alloc((size_t)NN * 4);
    float* attv  = (float*)alloc((size_t)NN * 4);
    int*  epack  = (int*)alloc((size_t)EE * 4);
    u16*  wjB   = (u16*)alloc((size_t)4 * SMALLB_SZ * 2);
    u16*  linB  = (u16*)alloc((size_t)4 * SMALLB_SZ * 2);
    u16*  wcB   = (u16*)alloc((size_t)4 * SMALLB_SZ * 2);
    u16*  postB = (u16*)alloc((size_t)12 * SEGB_SZ * 2);
    u16*  corr  = outA;

    // ---- setup ----
    hipMemsetAsync(bns, 0, 4 * 256 * 4, stream);
    k_embed<<<(NN * 128 / 8 + 255) / 256, 256, 0, stream>>>(x, emb1_w, emb1_b, hb);
    k_build_csr<<<G_, 128, 0, stream>>>(src, dst, eattr, deg, rstart, epack);
    k_node_scalars<<<(NN + 255) / 256, 256, 0, stream>>>(deg, deg_hist, ampv, attv);
    k_build_etab<<<40, 128, 0, stream>>>(edge_tab, enc_w, enc_b, pre_w, pre_b, etab);
    k_fold_T<<<dim3(128, 12), 128, 0, stream>>>(pre_w, post_w, Tbuf);
    k_fold_Wc<<<(4 * 128 * 128 + 255) / 256, 256, 0, stream>>>(Tbuf, post_w, deg_hist, WcBuf);
    k_prep_B128<<<dim3(SMALLB_SZ / 256, 12), 256, 0, stream>>>(pre_w, lin_w, WcBuf, wjB, linB, wcB);
    k_prep_Bpost<<<dim3((SEGB_SZ + 255) / 256, 12), 256, 0, stream>>>(post_w, Tbuf, postB);

    for (int l = 0; l < 4; ++l) {
        const float* coefL = (l == 0) ? nullptr : coef + (size_t)(l - 1) * 256;
        // Ps = bn(h)@Wj ; corr = bn(h)@Wc   (dual via grid.y, 4 tiles/block)
        k_psgemm<<<dim3(NN / 256, 2), 256, 0, stream>>>(
            hb, coefL, wjB + (size_t)l * SMALLB_SZ, wcB + (size_t)l * SMALLB_SZ, Ps, corr);
        for (int c = 0; c < nch; ++c) {
            int g0 = c * GCH_;
            size_t r0 = (size_t)g0 * NPG;
            k_agg2<<<GCH_, 512, 0, stream>>>(Ps + r0 * 128, etab + l * 10 * F_,
                                             deg, rstart, epack, aggb, g0);
            k_post2<<<(int)(CH_ / 64), 256, 0, stream>>>(
                hb + r0 * 128, coefL, aggb, corr + r0 * 128,
                deg + r0, ampv + r0, attv + r0,
                postB + (size_t)(l * 3) * SEGB_SZ, post_b + l * F_, outA + r0 * 128);
        }
        // hb = outA @ lin_w + lin_b, BN stats fused (4 tiles/block)
        k_lin<<<NN / 256, 256, 0, stream>>>(outA, linB + (size_t)l * SMALLB_SZ,
                                            lin_b + l * F_, bns + (size_t)l * 256, hb);
        k_bn_coef<<<1, 128, 0, stream>>>(bns + (size_t)l * 256, bn_g + l * F_, bn_b + l * F_,
                                         coef + (size_t)l * 256);
    }

    k_pool_mlp<<<G_, 256, 0, stream>>>(hb, coef + 3 * 256,
                                       w1, b1, w2, b2, w3, b3, w4, b4, out);
}

// Round 18
// 1150.360 us; speedup vs baseline: 1.0502x; 1.0440x over previous
//
#include <hip/hip_runtime.h>
#include <math.h>

#define G_    1024
#define NPG   126
#define EPG   450
#define NN    (G_*NPG)      // 129024
#define EE    (G_*EPG)      // 460800
#define F_    126
#define EPSV  1e-5f
#define ZCAP  32768         // max deg==0 nodes (expected ~3630, binomial; huge margin)

#define KS32  40                      // 32x32 k-steps: 640/16
#define SEGB_SZ (KS32*4*64*8)         // 81920 shorts per (layer,seg)
#define SMALLB_SZ (4*8*64*8)          // 16384 shorts per 128x128 matrix (16x16 layout)

typedef unsigned short u16;
typedef unsigned int   u32;
typedef __attribute__((ext_vector_type(8))) short bf8v;    // 8 bf16 in 4 VGPRs
typedef __attribute__((ext_vector_type(4))) float f4v;
typedef __attribute__((ext_vector_type(16))) float f16v;   // 32x32 accumulator

union U4 { bf8v v; u32 a[4]; };

__device__ __forceinline__ u16 f2b(float f) {              // RNE f32 -> bf16
    u32 u = __float_as_uint(f);
    u += 0x7FFFu + ((u >> 16) & 1u);
    return (u16)(u >> 16);
}
__device__ __forceinline__ float b2f(u16 s) { return __uint_as_float(((u32)s) << 16); }
__device__ __forceinline__ float b2f_lo(u32 u) { return __uint_as_float(u << 16); }
__device__ __forceinline__ float b2f_hi(u32 u) { return __uint_as_float(u & 0xFFFF0000u); }

// BN(+ReLU)-on-load of an 8-wide bf16 A-fragment; coef = {scale[128], shift[128]}
__device__ __forceinline__ bf8v bn_load(const u16* __restrict__ p,
                                        const float* __restrict__ coef, int k0) {
    U4 r; r.v = *(const bf8v*)p;
    if (!coef) return r.v;
    f4v s0 = *(const f4v*)(coef + k0);
    f4v s1 = *(const f4v*)(coef + k0 + 4);
    f4v h0 = *(const f4v*)(coef + 128 + k0);
    f4v h1 = *(const f4v*)(coef + 128 + k0 + 4);
    float v[8];
#pragma unroll
    for (int i = 0; i < 4; ++i) { v[2 * i] = b2f_lo(r.a[i]); v[2 * i + 1] = b2f_hi(r.a[i]); }
    v[0] = fmaxf(v[0] * s0[0] + h0[0], 0.f); v[1] = fmaxf(v[1] * s0[1] + h0[1], 0.f);
    v[2] = fmaxf(v[2] * s0[2] + h0[2], 0.f); v[3] = fmaxf(v[3] * s0[3] + h0[3], 0.f);
    v[4] = fmaxf(v[4] * s1[0] + h1[0], 0.f); v[5] = fmaxf(v[5] * s1[1] + h1[1], 0.f);
    v[6] = fmaxf(v[6] * s1[2] + h1[2], 0.f); v[7] = fmaxf(v[7] * s1[3] + h1[3], 0.f);
    U4 o;
#pragma unroll
    for (int i = 0; i < 4; ++i) o.a[i] = (u32)f2b(v[2 * i]) | ((u32)f2b(v[2 * i + 1]) << 16);
    return o.v;
}

// ---------------- node embedding ----------------
__global__ void k_embed(const float* __restrict__ x, const float* __restrict__ w,
                        const float* __restrict__ b, u16* __restrict__ hb) {
    int idx = (blockIdx.x * 256 + threadIdx.x) * 8;
    if (idx >= NN * 128) return;
    int n = idx >> 7, f0 = idx & 127;
    float xr[5];
#pragma unroll
    for (int c = 0; c < 5; ++c) xr[c] = x[n * 5 + c];
    float v[8];
#pragma unroll
    for (int j = 0; j < 8; ++j) {
        int f = f0 + j;
        float s = 0.f;
        if (f < F_) {
            s = b[f];
#pragma unroll
            for (int c = 0; c < 5; ++c) s += xr[c] * w[c * F_ + f];
        }
        v[j] = s;
    }
    U4 o;
#pragma unroll
    for (int i = 0; i < 4; ++i) o.a[i] = (u32)f2b(v[2 * i]) | ((u32)f2b(v[2 * i + 1]) << 16);
    *(bf8v*)(hb + idx) = o.v;
}

// ---------------- per-graph CSR build ----------------
__global__ void k_build_csr(const int* __restrict__ src, const int* __restrict__ dst,
                            const int* __restrict__ attr,
                            int* __restrict__ deg, int* __restrict__ rstart,
                            int* __restrict__ epack) {
    int g = blockIdx.x;
    __shared__ int scnt[NPG];
    __shared__ int spos[NPG];
    int t = threadIdx.x;
    for (int j = t; j < NPG; j += blockDim.x) scnt[j] = 0;
    __syncthreads();
    int e0 = g * EPG;
    for (int i = t; i < EPG; i += blockDim.x) {
        int dl = dst[e0 + i] - g * NPG;
        atomicAdd(&scnt[dl], 1);
    }
    __syncthreads();
    if (t == 0) {
        int run = 0;
        for (int j = 0; j < NPG; ++j) { spos[j] = run; run += scnt[j]; }
    }
    __syncthreads();
    for (int j = t; j < NPG; j += blockDim.x) {
        deg[g * NPG + j]    = scnt[j];
        rstart[g * NPG + j] = e0 + spos[j];
    }
    __syncthreads();
    for (int j = t; j < NPG; j += blockDim.x) scnt[j] = 0;
    __syncthreads();
    for (int i = t; i < EPG; i += blockDim.x) {
        int e  = e0 + i;
        int dl = dst[e] - g * NPG;
        int p  = atomicAdd(&scnt[dl], 1);
        epack[e0 + spos[dl] + p] = (src[e] - g * NPG) | (attr[e] << 8);
    }
}

// ---------------- deg==0 compaction ----------------
__global__ void k_zlist(const int* __restrict__ deg, int* __restrict__ zmeta,
                        int* __restrict__ zlist, int* __restrict__ cmap) {
    int n = blockIdx.x * 256 + threadIdx.x;
    if (n >= NN) return;
    int m = -1;
    if (deg[n] == 0) {
        int idx = atomicAdd(zmeta, 1);
        if (idx < ZCAP) { zlist[idx] = n; m = idx; }
    }
    cmap[n] = m;
}

// ---------------- per-node degree scalers ----------------
__global__ void k_node_scalars(const int* __restrict__ deg, const int* __restrict__ deg_hist,
                               float* __restrict__ ampv, float* __restrict__ attv) {
    int n = blockIdx.x * blockDim.x + threadIdx.x;
    if (n >= NN) return;
    float sum = 0.f, sl = 0.f;
#pragma unroll
    for (int b = 0; b < 5; ++b) {
        float dh = (float)deg_hist[b];
        sum += dh;
        sl  += dh * logf((float)b + 1.f);
    }
    float avg_log = sl / sum;
    float cm = fmaxf((float)deg[n], 1.f);
    float la = logf(cm + 1.f);
    ampv[n] = la / avg_log;
    attv[n] = avg_log / la;
}

// ---------------- edge-attr table (fp32) ----------------
__global__ void k_build_etab(const float* __restrict__ edge_tab, const float* __restrict__ enc_w,
                             const float* __restrict__ enc_b, const float* __restrict__ pre_w,
                             const float* __restrict__ pre_b, float* __restrict__ etab) {
    int l = blockIdx.x / 10, a = blockIdx.x % 10;
    __shared__ float tmp[F_];
    int t = threadIdx.x;
    if (t < F_) {
        float s = enc_b[l * F_ + t];
        for (int c = 0; c < 50; ++c) s += edge_tab[a * 50 + c] * enc_w[(l * 50 + c) * F_ + t];
        tmp[t] = s;
    }
    __syncthreads();
    if (t < F_) {
        float s = pre_b[l * F_ + t];
        for (int j = 0; j < F_; ++j) s += tmp[j] * pre_w[((size_t)l * 378 + 252 + j) * F_ + t];
        etab[(l * 10 + a) * F_ + t] = s;
    }
}

// ------------- fold: T[l][seg][k][c] -------------
__global__ void k_fold_T(const float* __restrict__ pre_w, const float* __restrict__ post_w,
                         float* __restrict__ Tbuf) {
    int k = blockIdx.x;
    int y = blockIdx.y;
    int l = y / 3, seg = y % 3;
    int c = threadIdx.x;
    __shared__ float wi[128];
    wi[c] = (k < F_ && c < F_) ? pre_w[((size_t)l * 378 + k) * F_ + c] : 0.f;
    __syncthreads();
    float s = 0.f;
    if (k < F_ && c < F_) {
        const float* pw = post_w + (size_t)l * 1638 * F_;
        if (seg == 0) s = pw[(size_t)k * F_ + c];
        int base = 126 + seg * 504;
        for (int f = 0; f < F_; ++f) {
            float bs = pw[(size_t)(base + f) * F_ + c]
                     + pw[(size_t)(base + 126 + f) * F_ + c]
                     + pw[(size_t)(base + 252 + f) * F_ + c];
            s += wi[f] * bs;
        }
    }
    Tbuf[((size_t)y * 128 + k) * 128 + c] = s;
}

// ------------- Wc (deg==0 correction weights) -------------
__global__ void k_fold_Wc(const float* __restrict__ Tbuf, const float* __restrict__ post_w,
                          const int* __restrict__ deg_hist, float* __restrict__ WcBuf) {
    int idx = blockIdx.x * 256 + threadIdx.x;
    if (idx >= 4 * 128 * 128) return;
    int l = idx >> 14, k = (idx >> 7) & 127, c = idx & 127;
    float dsum = 0.f, dsl = 0.f;
#pragma unroll
    for (int b = 0; b < 5; ++b) {
        float dh = (float)deg_hist[b];
        dsum += dh; dsl += dh * logf((float)b + 1.f);
    }
    float avgl = dsl / dsum;
    float l2 = logf(2.f);
    float amp0 = l2 / avgl, att0 = avgl / l2;
    float t1 = Tbuf[((size_t)(l * 3 + 0) * 128 + k) * 128 + c];
    float t2 = Tbuf[((size_t)(l * 3 + 1) * 128 + k) * 128 + c];
    float t3 = Tbuf[((size_t)(l * 3 + 2) * 128 + k) * 128 + c];
    float b0 = (k < F_ && c < F_) ? post_w[((size_t)l * 1638 + k) * F_ + c] : 0.f;
    WcBuf[((size_t)l * 128 + k) * 128 + c] = -((t1 - b0) + amp0 * t2 + att0 * t3);
}

// ---------------- B prep (128x128, 16x16 frag layout) ----------------
__global__ void k_prep_B128(const float* __restrict__ pre_w, const float* __restrict__ lin_w,
                            const float* __restrict__ WcBuf,
                            u16* __restrict__ wjB, u16* __restrict__ linB,
                            u16* __restrict__ wcB) {
    int idx = blockIdx.x * 256 + threadIdx.x;
    int y = blockIdx.y;
    int l = y & 3, ty = y >> 2;
    int j = idx & 7, lane = (idx >> 3) & 63, pnl = (idx >> 9) & 7, ks = idx >> 12;
    int k = ks * 32 + (lane >> 4) * 8 + j;
    int c = pnl * 16 + (lane & 15);
    float v;
    if (ty == 2) {
        v = WcBuf[((size_t)l * 128 + k) * 128 + c];
    } else {
        const float* W = (ty == 0) ? pre_w + ((size_t)l * 378 + 126) * F_
                                   : lin_w + (size_t)l * F_ * F_;
        v = (k < F_ && c < F_) ? W[(size_t)k * F_ + c] : 0.f;
    }
    u16* out = ((ty == 0) ? wjB : (ty == 1) ? linB : wcB) + (size_t)l * SMALLB_SZ;
    out[idx] = f2b(v);
}

// post B per (l,seg), 32x32 frag layout, virtual K=640
__global__ void k_prep_Bpost(const float* __restrict__ post_w, const float* __restrict__ Tbuf,
                             u16* __restrict__ postB) {
    int idx = blockIdx.x * 256 + threadIdx.x;
    if (idx >= SEGB_SZ) return;
    int y = blockIdx.y;                 // l*3+seg
    int l = y / 3, seg = y % 3;
    int j = idx & 7, lane = (idx >> 3) & 63, cg = (idx >> 9) & 3, ks = idx >> 11;  // ks 0..39
    int c  = cg * 32 + (lane & 31);
    int vk = ks * 16 + (lane >> 5) * 8 + j;
    float val = 0.f;
    if (vk < 128) {
        val = Tbuf[((size_t)y * 128 + vk) * 128 + c];
    } else {
        int kv = vk - 128;
        int f = kv >> 2, t = kv & 3;
        if (f < F_ && c < F_)
            val = post_w[((size_t)l * 1638 + 126 + seg * 504 + t * 126 + f) * F_ + c];
    }
    postB[(size_t)y * SEGB_SZ + idx] = f2b(val);
}

// ------- K=128 GEMM (Ps), BN-on-load, B in regs, 4 tiles/block ------------------------------
__global__ __launch_bounds__(256) void k_psgemm(
        const u16* __restrict__ A0, const float* __restrict__ coef,
        const u16* __restrict__ Bv, u16* __restrict__ C) {
    int lane = threadIdx.x & 63, wid = threadIdx.x >> 6;
    int gq = lane >> 4, r15 = lane & 15;
    int wr = (wid >> 1) * 32, wc = (wid & 1) * 64;
    const u16* bp = Bv + ((size_t)(wc >> 4) * 64 + lane) * 8;
    bf8v bfr[16];
#pragma unroll
    for (int ks = 0; ks < 4; ++ks)
#pragma unroll
        for (int fc = 0; fc < 4; ++fc)
            bfr[ks * 4 + fc] = *(const bf8v*)(bp + (size_t)ks * 4096 + fc * 512);

#pragma unroll
    for (int t = 0; t < 4; ++t) {
        size_t rbase = ((size_t)blockIdx.x * 4 + t) * 64;
        size_t row0 = rbase + wr + r15;
        const u16* a0p = A0 + row0 * 128 + gq * 8;
        const u16* a1p = a0p + 16 * 128;
        f4v acc[2][4];
#pragma unroll
        for (int i = 0; i < 2; ++i)
#pragma unroll
            for (int j = 0; j < 4; ++j) acc[i][j] = (f4v){0.f, 0.f, 0.f, 0.f};
#pragma unroll
        for (int ks = 0; ks < 4; ++ks) {
            int k0 = ks * 32 + gq * 8;
            bf8v a0 = bn_load(a0p + ks * 32, coef, k0);
            bf8v a1 = bn_load(a1p + ks * 32, coef, k0);
#pragma unroll
            for (int fc = 0; fc < 4; ++fc) {
                acc[0][fc] = __builtin_amdgcn_mfma_f32_16x16x32_bf16(a0, bfr[ks * 4 + fc], acc[0][fc], 0, 0, 0);
                acc[1][fc] = __builtin_amdgcn_mfma_f32_16x16x32_bf16(a1, bfr[ks * 4 + fc], acc[1][fc], 0, 0, 0);
            }
        }
        int erow = (int)rbase + wr + gq * 4;
        int ecol = wc + r15;
#pragma unroll
        for (int fc = 0; fc < 4; ++fc) {
            int col = ecol + fc * 16;
#pragma unroll
            for (int fr = 0; fr < 2; ++fr)
#pragma unroll
                for (int r = 0; r < 4; ++r) {
                    size_t row = erow + fr * 16 + r;
                    C[row * 128 + col] = (col < F_) ? f2b(acc[fr][fc][r]) : (u16)0;
                }
        }
    }
}

// ------- compact corr GEMM: corrc[s] = bn(h[zlist[s]]) @ Wc  (only deg==0 rows) -------------
__global__ __launch_bounds__(256) void k_corr(
        const u16* __restrict__ hA, const float* __restrict__ coef,
        const int* __restrict__ zmeta, const int* __restrict__ zlist,
        const u16* __restrict__ Bv, u16* __restrict__ corrc) {
    int nz = zmeta[0];
    if (nz > ZCAP) nz = ZCAP;
    int rbase = blockIdx.x * 64;
    if (rbase >= nz) return;
    int lane = threadIdx.x & 63, wid = threadIdx.x >> 6;
    int gq = lane >> 4, r15 = lane & 15;
    int wr = (wid >> 1) * 32, wc = (wid & 1) * 64;
    const u16* bp = Bv + ((size_t)(wc >> 4) * 64 + lane) * 8;
    bf8v bfr[16];
#pragma unroll
    for (int ks = 0; ks < 4; ++ks)
#pragma unroll
        for (int fc = 0; fc < 4; ++fc)
            bfr[ks * 4 + fc] = *(const bf8v*)(bp + (size_t)ks * 4096 + fc * 512);

    int slot0 = rbase + wr + r15;
    int slot1 = slot0 + 16;
    int g0 = zlist[slot0 < nz ? slot0 : nz - 1];
    int g1 = zlist[slot1 < nz ? slot1 : nz - 1];
    const u16* a0p = hA + (size_t)g0 * 128 + gq * 8;
    const u16* a1p = hA + (size_t)g1 * 128 + gq * 8;
    f4v acc[2][4];
#pragma unroll
    for (int i = 0; i < 2; ++i)
#pragma unroll
        for (int j = 0; j < 4; ++j) acc[i][j] = (f4v){0.f, 0.f, 0.f, 0.f};
#pragma unroll
    for (int ks = 0; ks < 4; ++ks) {
        int k0 = ks * 32 + gq * 8;
        bf8v a0 = bn_load(a0p + ks * 32, coef, k0);
        bf8v a1 = bn_load(a1p + ks * 32, coef, k0);
#pragma unroll
        for (int fc = 0; fc < 4; ++fc) {
            acc[0][fc] = __builtin_amdgcn_mfma_f32_16x16x32_bf16(a0, bfr[ks * 4 + fc], acc[0][fc], 0, 0, 0);
            acc[1][fc] = __builtin_amdgcn_mfma_f32_16x16x32_bf16(a1, bfr[ks * 4 + fc], acc[1][fc], 0, 0, 0);
        }
    }
    int erow = rbase + wr + gq * 4;
    int ecol = wc + r15;
#pragma unroll
    for (int fc = 0; fc < 4; ++fc) {
        int col = ecol + fc * 16;
#pragma unroll
        for (int fr = 0; fr < 2; ++fr)
#pragma unroll
            for (int r = 0; r < 4; ++r) {
                int row = erow + fr * 16 + r;
                if (row < nz)
                    corrc[(size_t)row * 128 + col] = (col < F_) ? f2b(acc[fr][fc][r]) : (u16)0;
            }
    }
}

// ------- wave-uniform per-graph aggregation (8 waves/graph) -> aggb[node][512] bf16 ---------
__global__ __launch_bounds__(512) void k_agg2(
        const u16* __restrict__ Psc,
        const float* __restrict__ etab_l,
        const int* __restrict__ deg, const int* __restrict__ rstart,
        const int* __restrict__ epack,
        u16* __restrict__ aggc, int g0) {
    __shared__ u32  PsL[126 * 65];
    __shared__ float etLo[10 * 64];
    __shared__ float etHi[10 * 64];
    __shared__ u32  epL[EPG];
    __shared__ int  degL[NPG];
    __shared__ int  rlL[NPG];
    int gg = g0 + blockIdx.x;
    int tid = threadIdx.x;
    const u16* psrow = Psc + (size_t)blockIdx.x * NPG * 128;
    for (int i = tid; i < NPG * 16; i += 512) {
        int r = i >> 4, q = i & 15;
        U4 u; u.v = *(const bf8v*)(psrow + (size_t)r * 128 + q * 8);
        u32* dp = &PsL[r * 65 + q * 4];
        dp[0] = u.a[0]; dp[1] = u.a[1]; dp[2] = u.a[2]; dp[3] = u.a[3];
    }
    for (int i = tid; i < 640; i += 512) {
        int a = i >> 6, ln = i & 63;
        int f = 2 * ln;
        etLo[i] = (f < F_) ? etab_l[a * F_ + f] : 0.f;
        etHi[i] = (f + 1 < F_) ? etab_l[a * F_ + f + 1] : 0.f;
    }
    for (int e = tid; e < EPG; e += 512) epL[e] = (u32)epack[(size_t)gg * EPG + e];
    if (tid < NPG) {
        degL[tid] = deg[(size_t)gg * NPG + tid];
        rlL[tid]  = rstart[(size_t)gg * NPG + tid] - gg * EPG;
    }
    __syncthreads();

    int lane = tid & 63, wid = tid >> 6;
    for (int nd = wid; nd < NPG; nd += 8) {
        int dg = degL[nd], rl = rlL[nd];
        float s0 = 0.f, q0 = 0.f, s1 = 0.f, q1 = 0.f;
        float n0 = 3.4e38f, x0 = -3.4e38f, n1 = 3.4e38f, x1 = -3.4e38f;
        for (int e = 0; e < dg; ++e) {
            u32 pk = epL[rl + e];
            int sN = pk & 255, at = pk >> 8;
            u32 pv = PsL[sN * 65 + lane];
            float v0 = b2f_lo(pv) + etLo[at * 64 + lane];
            float v1 = b2f_hi(pv) + etHi[at * 64 + lane];
            s0 += v0; q0 += v0 * v0; n0 = fminf(n0, v0); x0 = fmaxf(x0, v0);
            s1 += v1; q1 += v1 * v1; n1 = fminf(n1, v1); x1 = fmaxf(x1, v1);
        }
        float m0, m1, d0, d1;
        if (dg == 0) {
            m0 = m1 = 0.f; n0 = x0 = n1 = x1 = 0.f;
            d0 = d1 = 0.0031622776601683794f;
        } else {
            float ic = 1.f / (float)dg;
            m0 = s0 * ic; m1 = s1 * ic;
            d0 = sqrtf(fmaxf(q0 * ic - m0 * m0, 0.f) + EPSV);
            d1 = sqrtf(fmaxf(q1 * ic - m1 * m1, 0.f) + EPSV);
        }
        U4 o;
        o.a[0] = (u32)f2b(m0) | ((u32)f2b(n0) << 16);
        o.a[1] = (u32)f2b(x0) | ((u32)f2b(d0) << 16);
        o.a[2] = (u32)f2b(m1) | ((u32)f2b(n1) << 16);
        o.a[3] = (u32)f2b(x1) | ((u32)f2b(d1) << 16);
        *(bf8v*)(aggc + ((size_t)blockIdx.x * NPG + nd) * 512 + lane * 8) = o.v;
    }
}

// ------- post GEMM, 32x32x16 MFMA, wave tile 64 rows x 32 cols, B double-buffered -----------
// out = [h|vstat]@(T1;B1) + amp*(..2) + att*(..3) + bias (+corrc if cmap>=0)
__global__ __launch_bounds__(256) void k_post2(
        const u16* __restrict__ hA, const float* __restrict__ coef,
        const u16* __restrict__ aggc,
        const int* __restrict__ cmapc, const u16* __restrict__ corrc,
        const float* __restrict__ ampc, const float* __restrict__ attc,
        const u16* __restrict__ postB_l, const float* __restrict__ bias,
        u16* __restrict__ outC) {
    int lane = threadIdx.x & 63, cgw = threadIdx.x >> 6;   // col-group 0..3
    int r31 = lane & 31, kg = lane >> 5;
    size_t rbase = (size_t)blockIdx.x * 64;
    const u16* h0 = hA + (rbase + r31) * 128 + kg * 8;
    const u16* h1 = h0 + 32 * 128;
    const u16* g0 = aggc + (rbase + r31) * 512 + kg * 8;
    const u16* g1 = g0 + 32 * 512;
    const u16* bp = postB_l + ((size_t)cgw * 64 + lane) * 8;   // + ks*2048 + seg*SEGB_SZ

    f16v acc[3][2];
#pragma unroll
    for (int s = 0; s < 3; ++s)
#pragma unroll
        for (int i = 0; i < 2; ++i)
#pragma unroll
            for (int r = 0; r < 16; ++r) acc[s][i][r] = 0.f;

    bf8v bc0 = *(const bf8v*)(bp);
    bf8v bc1 = *(const bf8v*)(bp + SEGB_SZ);
    bf8v bc2 = *(const bf8v*)(bp + 2 * SEGB_SZ);

#pragma unroll 4
    for (int ks = 0; ks < KS32; ++ks) {
        // prefetch next step's B fragments
        bf8v bn0, bn1, bn2;
        if (ks < KS32 - 1) {
            const u16* bn = bp + (size_t)(ks + 1) * 2048;
            bn0 = *(const bf8v*)(bn);
            bn1 = *(const bf8v*)(bn + SEGB_SZ);
            bn2 = *(const bf8v*)(bn + 2 * SEGB_SZ);
        }
        bf8v a0, a1;
        if (ks < 8) {
            int k0 = ks * 16 + kg * 8;
            a0 = bn_load(h0 + ks * 16, coef, k0);
            a1 = bn_load(h1 + ks * 16, coef, k0);
        } else {
            int off = (ks - 8) * 16;
            a0 = *(const bf8v*)(g0 + off);
            a1 = *(const bf8v*)(g1 + off);
        }
        acc[0][0] = __builtin_amdgcn_mfma_f32_32x32x16_bf16(a0, bc0, acc[0][0], 0, 0, 0);
        acc[0][1] = __builtin_amdgcn_mfma_f32_32x32x16_bf16(a1, bc0, acc[0][1], 0, 0, 0);
        acc[1][0] = __builtin_amdgcn_mfma_f32_32x32x16_bf16(a0, bc1, acc[1][0], 0, 0, 0);
        acc[1][1] = __builtin_amdgcn_mfma_f32_32x32x16_bf16(a1, bc1, acc[1][1], 0, 0, 0);
        acc[2][0] = __builtin_amdgcn_mfma_f32_32x32x16_bf16(a0, bc2, acc[2][0], 0, 0, 0);
        acc[2][1] = __builtin_amdgcn_mfma_f32_32x32x16_bf16(a1, bc2, acc[2][1], 0, 0, 0);
        bc0 = bn0; bc1 = bn1; bc2 = bn2;
    }

    // epilogue: C/D map (32x32): col = lane&31, row = (r&3) + 8*(r>>2) + 4*(lane>>5)
    int ecol = cgw * 32 + r31;
    float bv = (ecol < F_) ? bias[ecol] : 0.f;
#pragma unroll
    for (int rf = 0; rf < 2; ++rf) {
#pragma unroll
        for (int r = 0; r < 16; ++r) {
            int rowl = rf * 32 + (r & 3) + 8 * (r >> 2) + 4 * kg;
            size_t row = rbase + rowl;
            float am = ampc[row], at = attc[row];
            int cm = cmapc[row];
            float val = acc[0][rf][r] + am * acc[1][rf][r] + at * acc[2][rf][r];
            u16 ov = 0;
            if (ecol < F_) {
                val += bv;
                if (cm >= 0) val += b2f(corrc[(size_t)cm * 128 + ecol]);
                ov = f2b(val);
            }
            outC[row * 128 + ecol] = ov;
        }
    }
}

// ------- lin GEMM (K=128) + fused BN stats, B in regs, 4 tiles/block ------------------------
__global__ __launch_bounds__(256) void k_lin(
        const u16* __restrict__ A0, const u16* __restrict__ Bv,
        const float* __restrict__ bias, float* __restrict__ bns,
        u16* __restrict__ C) {
    __shared__ float ldsS[128];
    __shared__ float ldsQ[128];
    int tid = threadIdx.x;
    if (tid < 128) { ldsS[tid] = 0.f; ldsQ[tid] = 0.f; }
    __syncthreads();
    int lane = tid & 63, wid = tid >> 6;
    int gq = lane >> 4, r15 = lane & 15;
    int wr = (wid >> 1) * 32, wc = (wid & 1) * 64;
    const u16* bp = Bv + ((size_t)(wc >> 4) * 64 + lane) * 8;
    bf8v bfr[16];
#pragma unroll
    for (int ks = 0; ks < 4; ++ks)
#pragma unroll
        for (int fc = 0; fc < 4; ++fc)
            bfr[ks * 4 + fc] = *(const bf8v*)(bp + (size_t)ks * 4096 + fc * 512);
    int ecol = wc + r15;
    float bv4[4], sc4[4] = {0.f, 0.f, 0.f, 0.f}, sq4[4] = {0.f, 0.f, 0.f, 0.f};
#pragma unroll
    for (int fc = 0; fc < 4; ++fc) {
        int col = ecol + fc * 16;
        bv4[fc] = (col < F_) ? bias[col] : 0.f;
    }

#pragma unroll
    for (int t = 0; t < 4; ++t) {
        size_t rbase = ((size_t)blockIdx.x * 4 + t) * 64;
        size_t row0 = rbase + wr + r15;
        const u16* a0p = A0 + row0 * 128 + gq * 8;
        const u16* a1p = a0p + 16 * 128;
        f4v acc[2][4];
#pragma unroll
        for (int i = 0; i < 2; ++i)
#pragma unroll
            for (int j = 0; j < 4; ++j) acc[i][j] = (f4v){0.f, 0.f, 0.f, 0.f};
#pragma unroll
        for (int ks = 0; ks < 4; ++ks) {
            bf8v a0 = *(const bf8v*)(a0p + ks * 32);
            bf8v a1 = *(const bf8v*)(a1p + ks * 32);
#pragma unroll
            for (int fc = 0; fc < 4; ++fc) {
                acc[0][fc] = __builtin_amdgcn_mfma_f32_16x16x32_bf16(a0, bfr[ks * 4 + fc], acc[0][fc], 0, 0, 0);
                acc[1][fc] = __builtin_amdgcn_mfma_f32_16x16x32_bf16(a1, bfr[ks * 4 + fc], acc[1][fc], 0, 0, 0);
            }
        }
        int erow = (int)rbase + wr + gq * 4;
#pragma unroll
        for (int fc = 0; fc < 4; ++fc) {
            int col = ecol + fc * 16;
#pragma unroll
            for (int fr = 0; fr < 2; ++fr)
#pragma unroll
                for (int r = 0; r < 4; ++r) {
                    size_t row = erow + fr * 16 + r;
                    float val = acc[fr][fc][r] + bv4[fc];
                    sc4[fc] += val; sq4[fc] += val * val;
                    C[row * 128 + col] = (col < F_) ? f2b(val) : (u16)0;
                }
        }
    }
#pragma unroll
    for (int fc = 0; fc < 4; ++fc) {
        int col = ecol + fc * 16;
        atomicAdd(&ldsS[col], sc4[fc]);
        atomicAdd(&ldsQ[col], sq4[fc]);
    }
    __syncthreads();
    if (tid < 128) {
        atomicAdd(&bns[tid], ldsS[tid]);
        atomicAdd(&bns[128 + tid], ldsQ[tid]);
    }
}

// ---------------- BN coefficients ----------------
__global__ void k_bn_coef(const float* __restrict__ bns, const float* __restrict__ g,
                          const float* __restrict__ b, float* __restrict__ coef) {
    int f = threadIdx.x;
    float sc = 0.f, sh = 0.f;
    if (f < F_) {
        float mu  = bns[f] * (1.f / NN);
        float var = bns[128 + f] * (1.f / NN) - mu * mu;
        float r = rsqrtf(fmaxf(var, 0.f) + EPSV);
        sc = g[f] * r;
        sh = b[f] - mu * sc;
    }
    coef[f] = sc;
    coef[128 + f] = sh;
}

// ---------------- pool (BN-on-load) + 4-layer MLP head (fp32) --------------
__global__ __launch_bounds__(256) void k_pool_mlp(const u16* __restrict__ hb,
        const float* __restrict__ coef,
        const float* __restrict__ w1, const float* __restrict__ b1,
        const float* __restrict__ w2, const float* __restrict__ b2,
        const float* __restrict__ w3, const float* __restrict__ b3,
        const float* __restrict__ w4, const float* __restrict__ b4,
        float* __restrict__ out) {
    int gg = blockIdx.x;
    __shared__ float lsum[16][128];
    __shared__ float p[128];
    __shared__ float z1[100];
    __shared__ float z2[50];
    __shared__ float z3[25];
    int t = threadIdx.x;
    int cg = t & 15, rs = t >> 4;
    float sc[8], sh[8];
#pragma unroll
    for (int j = 0; j < 8; ++j) { sc[j] = coef[cg * 8 + j]; sh[j] = coef[128 + cg * 8 + j]; }
    const u16* hbase = hb + (size_t)gg * NPG * 128 + cg * 8;
    float a8[8] = {};
    for (int r = rs; r < NPG; r += 16) {
        U4 u;
        u.v = *(const bf8v*)(hbase + (size_t)r * 128);
        float v[8];
#pragma unroll
        for (int i = 0; i < 4; ++i) { v[2 * i] = b2f_lo(u.a[i]); v[2 * i + 1] = b2f_hi(u.a[i]); }
#pragma unroll
        for (int j = 0; j < 8; ++j) a8[j] += fmaxf(v[j] * sc[j] + sh[j], 0.f);
    }
#pragma unroll
    for (int j = 0; j < 8; ++j) lsum[rs][cg * 8 + j] = a8[j];
    __syncthreads();
    if (t < 128) {
        float s = 0.f;
#pragma unroll
        for (int k = 0; k < 16; ++k) s += lsum[k][t];
        p[t] = s;
    }
    __syncthreads();
    if (t < 100) {
        float s = b1[t];
        for (int c = 0; c < F_; ++c) s += p[c] * w1[c * 100 + t];
        z1[t] = fmaxf(s, 0.f);
    }
    __syncthreads();
    if (t < 50) {
        float s = b2[t];
        for (int c = 0; c < 100; ++c) s += z1[c] * w2[c * 50 + t];
        z2[t] = fmaxf(s, 0.f);
    }
    __syncthreads();
    if (t < 25) {
        float s = b3[t];
        for (int c = 0; c < 50; ++c) s += z2[c] * w3[c * 25 + t];
        z3[t] = fmaxf(s, 0.f);
    }
    __syncthreads();
    if (t == 0) {
        float s = b4[0];
        for (int c = 0; c < 25; ++c) s += z3[c] * w4[c];
        out[gg] = s;
    }
}

extern "C" void kernel_launch(void* const* d_in, const int* in_sizes, int n_in,
                              void* d_out, int out_size, void* d_ws, size_t ws_size,
                              hipStream_t stream) {
    const float* x        = (const float*)d_in[0];
    const int*   ei       = (const int*)d_in[1];
    const int*   src      = ei;
    const int*   dst      = ei + EE;
    const int*   eattr    = (const int*)d_in[2];
    const int*   deg_hist = (const int*)d_in[4];
    const float* emb1_w = (const float*)d_in[5];
    const float* emb1_b = (const float*)d_in[6];
    const float* edge_tab = (const float*)d_in[7];
    const float* enc_w  = (const float*)d_in[8];
    const float* enc_b  = (const float*)d_in[9];
    const float* pre_w  = (const float*)d_in[10];
    const float* pre_b  = (const float*)d_in[11];
    const float* post_w = (const float*)d_in[12];
    const float* post_b = (const float*)d_in[13];
    const float* lin_w  = (const float*)d_in[14];
    const float* lin_b  = (const float*)d_in[15];
    const float* bn_g   = (const float*)d_in[16];
    const float* bn_b   = (const float*)d_in[17];
    const float* w1 = (const float*)d_in[18];
    const float* b1 = (const float*)d_in[19];
    const float* w2 = (const float*)d_in[20];
    const float* b2 = (const float*)d_in[21];
    const float* w3 = (const float*)d_in[22];
    const float* b3 = (const float*)d_in[23];
    const float* w4 = (const float*)d_in[24];
    const float* b4 = (const float*)d_in[25];
    float* out = (float*)d_out;

    // ---- workspace layout; chunk count chosen from ws_size ----
    size_t fixedB = 0;
    {
        fixedB += 3 * ((size_t)NN * 128 * 2 + 256);          // hb, Ps, outA
        fixedB += (size_t)ZCAP * 128 * 2 + 256;              // corrc
        fixedB += 4 * 10 * F_ * 4 + 256;                     // etab
        fixedB += (size_t)12 * 128 * 128 * 4 + 256;          // Tbuf
        fixedB += (size_t)4 * 128 * 128 * 4 + 256;           // WcBuf
        fixedB += 2 * (4 * 256 * 4 + 256);                   // bns, coef
        fixedB += 2 * ((size_t)NN * 4 + 256);                // deg, rstart
        fixedB += 2 * ((size_t)NN * 4 + 256);                // ampv, attv
        fixedB += (size_t)NN * 4 + 256;                      // cmap
        fixedB += (size_t)ZCAP * 4 + 512;                    // zlist + zmeta
        fixedB += (size_t)EE * 4 + 256;                      // epack
        fixedB += 3 * ((size_t)4 * SMALLB_SZ * 2 + 256);     // wjB, linB, wcB
        fixedB += (size_t)12 * SEGB_SZ * 2 + 256;            // postB
    }
    int nch = (ws_size >= fixedB + (size_t)NN * 512 * 2 + 256) ? 1 : 2;
    int GCH_ = G_ / nch;
    size_t CH_ = (size_t)NN / nch;

    char* base = (char*)d_ws;
    size_t o = 0;
    auto alloc = [&](size_t bytes) { char* r = base + o; o = (o + bytes + 255) & ~(size_t)255; return r; };
    u16*  hb    = (u16*)  alloc((size_t)NN * 128 * 2);
    u16*  Ps    = (u16*)  alloc((size_t)NN * 128 * 2);
    u16*  outA  = (u16*)  alloc((size_t)NN * 128 * 2);
    u16*  corrc = (u16*)  alloc((size_t)ZCAP * 128 * 2);
    u16*  aggb  = (u16*)  alloc(CH_ * 512 * 2);
    float* etab = (float*)alloc(4 * 10 * F_ * 4);
    float* Tbuf = (float*)alloc((size_t)12 * 128 * 128 * 4);
    float* WcBuf= (float*)alloc((size_t)4 * 128 * 128 * 4);
    float* bns  = (float*)alloc(4 * 256 * 4);
    float* coef = (float*)alloc(4 * 256 * 4);
    int*  deg    = (int*)alloc((size_t)NN * 4);
    int*  rstart = (int*)alloc((size_t)NN * 4);
    float* ampv  = (float*)alloc((size_t)NN * 4);
    float* attv  = (float*)alloc((size_t)NN * 4);
    int*  cmap   = (int*)alloc((size_t)NN * 4);
    int*  zmeta  = (int*)alloc(256);
    int*  zlist  = (int*)alloc((size_t)ZCAP * 4);
    int*  epack  = (int*)alloc((size_t)EE * 4);
    u16*  wjB   = (u16*)alloc((size_t)4 * SMALLB_SZ * 2);
    u16*  linB  = (u16*)alloc((size_t)4 * SMALLB_SZ * 2);
    u16*  wcB   = (u16*)alloc((size_t)4 * SMALLB_SZ * 2);
    u16*  postB = (u16*)alloc((size_t)12 * SEGB_SZ * 2);

    // ---- setup ----
    hipMemsetAsync(bns, 0, 4 * 256 * 4, stream);
    hipMemsetAsync(zmeta, 0, 256, stream);
    k_embed<<<(NN * 128 / 8 + 255) / 256, 256, 0, stream>>>(x, emb1_w, emb1_b, hb);
    k_build_csr<<<G_, 128, 0, stream>>>(src, dst, eattr, deg, rstart, epack);
    k_zlist<<<(NN + 255) / 256, 256, 0, stream>>>(deg, zmeta, zlist, cmap);
    k_node_scalars<<<(NN + 255) / 256, 256, 0, stream>>>(deg, deg_hist, ampv, attv);
    k_build_etab<<<40, 128, 0, stream>>>(edge_tab, enc_w, enc_b, pre_w, pre_b, etab);
    k_fold_T<<<dim3(128, 12), 128, 0, stream>>>(pre_w, post_w, Tbuf);
    k_fold_Wc<<<(4 * 128 * 128 + 255) / 256, 256, 0, stream>>>(Tbuf, post_w, deg_hist, WcBuf);
    k_prep_B128<<<dim3(SMALLB_SZ / 256, 12), 256, 0, stream>>>(pre_w, lin_w, WcBuf, wjB, linB, wcB);
    k_prep_Bpost<<<dim3((SEGB_SZ + 255) / 256, 12), 256, 0, stream>>>(post_w, Tbuf, postB);

    for (int l = 0; l < 4; ++l) {
        const float* coefL = (l == 0) ? nullptr : coef + (size_t)(l - 1) * 256;
        // Ps = bn(h)@Wj   (single, 4 tiles/block)
        k_psgemm<<<NN / 256, 256, 0, stream>>>(hb, coefL, wjB + (size_t)l * SMALLB_SZ, Ps);
        // corrc = bn(h[deg==0])@Wc  (compact; most blocks early-exit)
        k_corr<<<ZCAP / 64, 256, 0, stream>>>(hb, coefL, zmeta, zlist,
                                              wcB + (size_t)l * SMALLB_SZ, corrc);
        for (int c = 0; c < nch; ++c) {
            int g0 = c * GCH_;
            size_t r0 = (size_t)g0 * NPG;
            k_agg2<<<GCH_, 512, 0, stream>>>(Ps + r0 * 128, etab + l * 10 * F_,
                                             deg, rstart, epack, aggb, g0);
            k_post2<<<(int)(CH_ / 64), 256, 0, stream>>>(
                hb + r0 * 128, coefL, aggb, cmap + r0, corrc,
                ampv + r0, attv + r0,
                postB + (size_t)(l * 3) * SEGB_SZ, post_b + l * F_, outA + r0 * 128);
        }
        // hb = outA @ lin_w + lin_b, BN stats fused (4 tiles/block)
        k_lin<<<NN / 256, 256, 0, stream>>>(outA, linB + (size_t)l * SMALLB_SZ,
                                            lin_b + l * F_, bns + (size_t)l * 256, hb);
        k_bn_coef<<<1, 128, 0, stream>>>(bns + (size_t)l * 256, bn_g + l * F_, bn_b + l * F_,
                                         coef + (size_t)l * 256);
    }

    k_pool_mlp<<<G_, 256, 0, stream>>>(hb, coef + 3 * 256,
                                       w1, b1, w2, b2, w3, b3, w4, b4, out);
}